// Round 1
// baseline (519.073 us; speedup 1.0000x reference)
//
#include <hip/hip_runtime.h>
#include <math.h>

#define N_NODES 50000
#define N_EDGES 800000
#define HID 128
#define HEADS 8
#define HDIM 16

// ---------------- kernel 0: fold query into q/k biases ----------------
// q = nq @ Wq + bq where nq = [nf, query]; fold query@Wq[128:256] into bias.
__global__ void bias_fold_kernel(const float* __restrict__ query,
                                 const float* __restrict__ Wq, const float* __restrict__ bq,
                                 const float* __restrict__ Wk, const float* __restrict__ bk,
                                 float* __restrict__ bqe, float* __restrict__ bke) {
    int j = threadIdx.x;  // 128 threads
    float aq = bq[j], ak = bk[j];
    for (int i = 0; i < HID; ++i) {
        float qv = query[i];
        aq += qv * Wq[(HID + i) * HID + j];
        ak += qv * Wk[(HID + i) * HID + j];
    }
    bqe[j] = aq;
    bke[j] = ak;
}

// ---------------- kernel 1: fused QKV GEMM (fp32, register-tiled) ----------------
// 64 rows/block, 256 threads: thread = 8 rows x 4 cols, i-unrolled by 4 (float4).
__global__ __launch_bounds__(256) void qkv_kernel(
    const float* __restrict__ nf,
    const float* __restrict__ Wq, const float* __restrict__ Wk, const float* __restrict__ Wv,
    const float* __restrict__ bqe, const float* __restrict__ bke, const float* __restrict__ bv,
    float* __restrict__ q, float* __restrict__ k, float* __restrict__ v) {
    __shared__ float nfs[64 * HID];  // 32 KB
    int row0 = blockIdx.x * 64;
    int nrows = N_NODES - row0; if (nrows > 64) nrows = 64;
    for (int t = threadIdx.x; t < nrows * HID; t += 256) nfs[t] = nf[row0 * HID + t];
    __syncthreads();

    int jg = (threadIdx.x & 31) * 4;   // col base (0..124)
    int rg = (threadIdx.x >> 5) * 8;   // row base within tile (0..56)

    const float* Ws[3]   = {Wq, Wk, Wv};
    const float* bs[3]   = {bqe, bke, bv};
    float*       outs[3] = {q, k, v};

    #pragma unroll
    for (int m = 0; m < 3; ++m) {
        const float* W = Ws[m];
        float4 acc[8];
        #pragma unroll
        for (int r = 0; r < 8; ++r) acc[r] = make_float4(0.f, 0.f, 0.f, 0.f);
        for (int i = 0; i < HID; i += 4) {
            float4 w0 = *(const float4*)(W + (i + 0) * HID + jg);
            float4 w1 = *(const float4*)(W + (i + 1) * HID + jg);
            float4 w2 = *(const float4*)(W + (i + 2) * HID + jg);
            float4 w3 = *(const float4*)(W + (i + 3) * HID + jg);
            #pragma unroll
            for (int r = 0; r < 8; ++r) {
                float4 a = *(const float4*)(&nfs[(rg + r) * HID + i]);
                acc[r].x += a.x * w0.x + a.y * w1.x + a.z * w2.x + a.w * w3.x;
                acc[r].y += a.x * w0.y + a.y * w1.y + a.z * w2.y + a.w * w3.y;
                acc[r].z += a.x * w0.z + a.y * w1.z + a.z * w2.z + a.w * w3.z;
                acc[r].w += a.x * w0.w + a.y * w1.w + a.z * w2.w + a.w * w3.w;
            }
        }
        float4 bias = *(const float4*)(bs[m] + jg);
        float* out = outs[m];
        #pragma unroll
        for (int r = 0; r < 8; ++r) {
            int row = rg + r;
            if (row < nrows) {
                float4 o;
                o.x = acc[r].x + bias.x; o.y = acc[r].y + bias.y;
                o.z = acc[r].z + bias.z; o.w = acc[r].w + bias.w;
                *(float4*)(out + (size_t)(row0 + row) * HID + jg) = o;
            }
        }
    }
}

// ---------------- kernel 5: out = A @ Wo + bo, in-place on A ----------------
__global__ __launch_bounds__(256) void out_gemm_kernel(
    float* __restrict__ A, const float* __restrict__ W, const float* __restrict__ bias) {
    __shared__ float as[64 * HID];
    int row0 = blockIdx.x * 64;
    int nrows = N_NODES - row0; if (nrows > 64) nrows = 64;
    for (int t = threadIdx.x; t < nrows * HID; t += 256) as[t] = A[row0 * HID + t];
    __syncthreads();  // all reads of our rows done before any overwrite
    int jg = (threadIdx.x & 31) * 4;
    int rg = (threadIdx.x >> 5) * 8;
    float4 acc[8];
    #pragma unroll
    for (int r = 0; r < 8; ++r) acc[r] = make_float4(0.f, 0.f, 0.f, 0.f);
    for (int i = 0; i < HID; i += 4) {
        float4 w0 = *(const float4*)(W + (i + 0) * HID + jg);
        float4 w1 = *(const float4*)(W + (i + 1) * HID + jg);
        float4 w2 = *(const float4*)(W + (i + 2) * HID + jg);
        float4 w3 = *(const float4*)(W + (i + 3) * HID + jg);
        #pragma unroll
        for (int r = 0; r < 8; ++r) {
            float4 a = *(const float4*)(&as[(rg + r) * HID + i]);
            acc[r].x += a.x * w0.x + a.y * w1.x + a.z * w2.x + a.w * w3.x;
            acc[r].y += a.x * w0.y + a.y * w1.y + a.z * w2.y + a.w * w3.y;
            acc[r].z += a.x * w0.z + a.y * w1.z + a.z * w2.z + a.w * w3.z;
            acc[r].w += a.x * w0.w + a.y * w1.w + a.z * w2.w + a.w * w3.w;
        }
    }
    float4 b = *(const float4*)(bias + jg);
    #pragma unroll
    for (int r = 0; r < 8; ++r) {
        int row = rg + r;
        if (row < nrows) {
            float4 o;
            o.x = acc[r].x + b.x; o.y = acc[r].y + b.y;
            o.z = acc[r].z + b.z; o.w = acc[r].w + b.w;
            *(float4*)(A + (size_t)(row0 + row) * HID + jg) = o;
        }
    }
}

// ---------------- CSR build ----------------
__global__ void count_kernel(const int* __restrict__ ei, int* __restrict__ counts) {
    int e = blockIdx.x * 256 + threadIdx.x;
    if (e < N_EDGES) atomicAdd(&counts[ei[N_EDGES + e]], 1);
}

__global__ __launch_bounds__(1024) void scan_kernel(const int* __restrict__ counts,
                                                    int* __restrict__ row_start) {
    __shared__ int wsum[16];
    int tid = threadIdx.x, lane = tid & 63, w = tid >> 6;
    int carry = 0;
    for (int base = 0; base < N_NODES; base += 1024) {
        int i = base + tid;
        int x = (i < N_NODES) ? counts[i] : 0;
        int val = x;
        #pragma unroll
        for (int off = 1; off < 64; off <<= 1) {
            int y = __shfl_up(val, off);
            if (lane >= off) val += y;
        }
        if (lane == 63) wsum[w] = val;
        __syncthreads();
        if (w == 0) {
            int s = (lane < 16) ? wsum[lane] : 0;
            #pragma unroll
            for (int off = 1; off < 16; off <<= 1) {
                int y = __shfl_up(s, off);
                if (lane >= off) s += y;
            }
            if (lane < 16) wsum[lane] = s;
        }
        __syncthreads();
        int woff = (w > 0) ? wsum[w - 1] : 0;
        int incl = val + woff;
        if (i < N_NODES) row_start[i] = carry + incl - x;  // exclusive scan
        carry += wsum[15];
        __syncthreads();
    }
    if (tid == 0) row_start[N_NODES] = carry;
}

__global__ void scatter_kernel(const int* __restrict__ ei, const int* __restrict__ et,
                               const int* __restrict__ row_start, int* __restrict__ cursor,
                               unsigned int* __restrict__ csr) {
    int e = blockIdx.x * 256 + threadIdx.x;
    if (e < N_EDGES) {
        int dst = ei[N_EDGES + e];
        int src = ei[e];
        int pos = atomicAdd(&cursor[dst], 1);
        csr[row_start[dst] + pos] = ((unsigned int)et[e] << 18) | (unsigned int)src;
    }
}

// ---------------- kernel 4: wave-per-node attention ----------------
// lane = eloc*8 + h. No LDS, no atomics: butterfly shuffles for segment max/sum,
// shfl broadcast for the message accumulation.
__global__ __launch_bounds__(256) void attn_kernel(
    const float* __restrict__ q, const float* __restrict__ k, const float* __restrict__ v,
    const float* __restrict__ rel,
    const int* __restrict__ row_start, const unsigned int* __restrict__ csr,
    float* __restrict__ scores, float* __restrict__ out) {
    // grid = N_NODES/4 blocks of 256 (exact: 50000 % 4 == 0)
    int node = blockIdx.x * 4 + (threadIdx.x >> 6);
    int lane = threadIdx.x & 63;
    int h = lane & 7;
    int rs = row_start[node], re = row_start[node + 1];
    int deg = re - rs;

    const float4* qp = (const float4*)(q + (size_t)node * HID + h * HDIM);
    float4 q0 = qp[0], q1 = qp[1], q2 = qp[2], q3 = qp[3];

    // Phase A: scores + running max (clamped at 0 per reference)
    float smax = 0.0f;
    for (int base = 0; base < deg; base += 8) {
        int el = base + (lane >> 3);
        if (el < deg) {
            unsigned int pk = csr[rs + el];
            int src = pk & 0x3FFFF;
            int etv = (int)(pk >> 18);
            const float4* kp = (const float4*)(k + (size_t)src * HID + h * HDIM);
            const float4* rp = (const float4*)(rel + (size_t)etv * HID + h * HDIM);
            float4 k0 = kp[0], k1 = kp[1], k2 = kp[2], k3 = kp[3];
            float4 r0 = rp[0], r1 = rp[1], r2 = rp[2], r3 = rp[3];
            float s = q0.x * (k0.x + r0.x) + q0.y * (k0.y + r0.y) + q0.z * (k0.z + r0.z) + q0.w * (k0.w + r0.w)
                    + q1.x * (k1.x + r1.x) + q1.y * (k1.y + r1.y) + q1.z * (k1.z + r1.z) + q1.w * (k1.w + r1.w)
                    + q2.x * (k2.x + r2.x) + q2.y * (k2.y + r2.y) + q2.z * (k2.z + r2.z) + q2.w * (k2.w + r2.w)
                    + q3.x * (k3.x + r3.x) + q3.y * (k3.y + r3.y) + q3.z * (k3.z + r3.z) + q3.w * (k3.w + r3.w);
            s *= 0.25f;  // / sqrt(16)
            scores[(size_t)(rs + el) * 8 + h] = s;
            smax = fmaxf(smax, s);
        }
    }
    #pragma unroll
    for (int off = 8; off < 64; off <<= 1) smax = fmaxf(smax, __shfl_xor(smax, off));

    __syncthreads();  // drains vmcnt: our score stores visible to our re-reads

    // Phase B: sum of exp per head
    float ssum = 0.0f;
    for (int base = 0; base < deg; base += 8) {
        int el = base + (lane >> 3);
        if (el < deg) ssum += __expf(scores[(size_t)(rs + el) * 8 + h] - smax);
    }
    #pragma unroll
    for (int off = 8; off < 64; off <<= 1) ssum += __shfl_xor(ssum, off);

    // Phase C: message accumulation. lane owns dims {lane, 64+lane}.
    int h0 = lane >> 4;        // head of dim lane   (0..3)
    int h1 = 4 + (lane >> 4);  // head of dim 64+lane (4..7)
    float s0 = __shfl(ssum, h0);
    float s1 = __shfl(ssum, h1);
    float inv0 = 1.0f / (s0 + 1e-8f);
    float inv1 = 1.0f / (s1 + 1e-8f);
    float acc0 = 0.0f, acc1 = 0.0f;
    for (int base = 0; base < deg; base += 8) {
        int el = base + (lane >> 3);
        float p = 0.0f; int src = 0;
        if (el < deg) {
            unsigned int pk = csr[rs + el];
            src = pk & 0x3FFFF;
            p = __expf(scores[(size_t)(rs + el) * 8 + h] - smax);
        }
        int cnt = deg - base; if (cnt > 8) cnt = 8;
        for (int j = 0; j < cnt; ++j) {
            int   sj = __shfl(src, j * 8);
            float p0 = __shfl(p, j * 8 + h0);
            float p1 = __shfl(p, j * 8 + h1);
            acc0 += (p0 * inv0) * v[(size_t)sj * HID + lane];
            acc1 += (p1 * inv1) * v[(size_t)sj * HID + 64 + lane];
        }
    }
    out[(size_t)node * HID + lane] = acc0;
    out[(size_t)node * HID + 64 + lane] = acc1;
}

extern "C" void kernel_launch(void* const* d_in, const int* in_sizes, int n_in,
                              void* d_out, int out_size, void* d_ws, size_t ws_size,
                              hipStream_t stream) {
    const float* nf    = (const float*)d_in[0];
    const float* query = (const float*)d_in[1];
    const float* rel   = (const float*)d_in[2];
    const float* Wq    = (const float*)d_in[3];
    const float* bq    = (const float*)d_in[4];
    const float* Wk    = (const float*)d_in[5];
    const float* bk    = (const float*)d_in[6];
    const float* Wv    = (const float*)d_in[7];
    const float* bv    = (const float*)d_in[8];
    const float* Wo    = (const float*)d_in[9];
    const float* bo    = (const float*)d_in[10];
    const int*   ei    = (const int*)d_in[11];
    const int*   et    = (const int*)d_in[12];
    float* out = (float*)d_out;

    char* ws = (char*)d_ws;
    float* q       = (float*)ws;  ws += (size_t)N_NODES * HID * 4;
    float* kk      = (float*)ws;  ws += (size_t)N_NODES * HID * 4;
    float* vv      = (float*)ws;  ws += (size_t)N_NODES * HID * 4;
    float* scores  = (float*)ws;  ws += (size_t)N_EDGES * HEADS * 4;
    float* bqe     = (float*)ws;  ws += 128 * 4;
    float* bke     = (float*)ws;  ws += 128 * 4;
    int* row_start = (int*)ws;    ws += (size_t)(N_NODES + 1) * 4;
    int* counts    = (int*)ws;    ws += (size_t)N_NODES * 4;
    int* cursor    = (int*)ws;    ws += (size_t)N_NODES * 4;
    unsigned int* csr = (unsigned int*)ws;  ws += (size_t)N_EDGES * 4;

    hipMemsetAsync(counts, 0, (size_t)N_NODES * 4, stream);
    hipMemsetAsync(cursor, 0, (size_t)N_NODES * 4, stream);

    bias_fold_kernel<<<1, 128, 0, stream>>>(query, Wq, bq, Wk, bk, bqe, bke);
    qkv_kernel<<<(N_NODES + 63) / 64, 256, 0, stream>>>(nf, Wq, Wk, Wv, bqe, bke, bv, q, kk, vv);
    count_kernel<<<(N_EDGES + 255) / 256, 256, 0, stream>>>(ei, counts);
    scan_kernel<<<1, 1024, 0, stream>>>(counts, row_start);
    scatter_kernel<<<(N_EDGES + 255) / 256, 256, 0, stream>>>(ei, et, row_start, cursor, csr);
    attn_kernel<<<N_NODES / 4, 256, 0, stream>>>(q, kk, vv, rel, row_start, csr, scores, out);
    out_gemm_kernel<<<(N_NODES + 63) / 64, 256, 0, stream>>>(out, Wo, bo);
}

// Round 2
// 435.387 us; speedup vs baseline: 1.1922x; 1.1922x over previous
//
#include <hip/hip_runtime.h>
#include <math.h>

#define N_NODES 50000
#define N_EDGES 800000
#define HID 128
#define HEADS 8
#define HDIM 16
#define CAP 96  // max per-node edges kept in LDS; Poisson(16) max deg ~45, fallback to global beyond

__device__ __forceinline__ float bf_lo(unsigned int d) { return __uint_as_float(d << 16); }
__device__ __forceinline__ float bf_hi(unsigned int d) { return __uint_as_float(d & 0xFFFF0000u); }
__device__ __forceinline__ unsigned int pack_bf2(float a, float b) {
    unsigned int ua = __float_as_uint(a), ub = __float_as_uint(b);
    ua = (ua + 0x7FFFu + ((ua >> 16) & 1u)) >> 16;          // RNE
    ub = (ub + 0x7FFFu + ((ub >> 16) & 1u)) & 0xFFFF0000u;  // RNE, keep high
    return ua | ub;
}

// ---------------- kernel 0: fold query into q/k biases ----------------
__global__ void bias_fold_kernel(const float* __restrict__ query,
                                 const float* __restrict__ Wq, const float* __restrict__ bq,
                                 const float* __restrict__ Wk, const float* __restrict__ bk,
                                 float* __restrict__ bqe, float* __restrict__ bke) {
    int j = threadIdx.x;  // 128 threads
    float aq = bq[j], ak = bk[j];
    for (int i = 0; i < HID; ++i) {
        float qv = query[i];
        aq += qv * Wq[(HID + i) * HID + j];
        ak += qv * Wk[(HID + i) * HID + j];
    }
    bqe[j] = aq;
    bke[j] = ak;
}

// ---------------- kernel 1: fused QKV GEMM; q fp32, k/v packed bf16 ----------------
__global__ __launch_bounds__(256) void qkv_kernel(
    const float* __restrict__ nf,
    const float* __restrict__ Wq, const float* __restrict__ Wk, const float* __restrict__ Wv,
    const float* __restrict__ bqe, const float* __restrict__ bke, const float* __restrict__ bv,
    float* __restrict__ q, unsigned int* __restrict__ kbf, unsigned int* __restrict__ vbf) {
    __shared__ float nfs[64 * HID];  // 32 KB
    int row0 = blockIdx.x * 64;
    int nrows = N_NODES - row0; if (nrows > 64) nrows = 64;
    for (int t = threadIdx.x; t < nrows * HID; t += 256) nfs[t] = nf[row0 * HID + t];
    __syncthreads();

    int jg = (threadIdx.x & 31) * 4;   // col base
    int rg = (threadIdx.x >> 5) * 8;   // row base in tile

    const float* Ws[3] = {Wq, Wk, Wv};
    const float* bs[3] = {bqe, bke, bv};

    #pragma unroll
    for (int m = 0; m < 3; ++m) {
        const float* W = Ws[m];
        float4 acc[8];
        #pragma unroll
        for (int r = 0; r < 8; ++r) acc[r] = make_float4(0.f, 0.f, 0.f, 0.f);
        for (int i = 0; i < HID; i += 4) {
            float4 w0 = *(const float4*)(W + (i + 0) * HID + jg);
            float4 w1 = *(const float4*)(W + (i + 1) * HID + jg);
            float4 w2 = *(const float4*)(W + (i + 2) * HID + jg);
            float4 w3 = *(const float4*)(W + (i + 3) * HID + jg);
            #pragma unroll
            for (int r = 0; r < 8; ++r) {
                float4 a = *(const float4*)(&nfs[(rg + r) * HID + i]);
                acc[r].x += a.x * w0.x + a.y * w1.x + a.z * w2.x + a.w * w3.x;
                acc[r].y += a.x * w0.y + a.y * w1.y + a.z * w2.y + a.w * w3.y;
                acc[r].z += a.x * w0.z + a.y * w1.z + a.z * w2.z + a.w * w3.z;
                acc[r].w += a.x * w0.w + a.y * w1.w + a.z * w2.w + a.w * w3.w;
            }
        }
        float4 bias = *(const float4*)(bs[m] + jg);
        #pragma unroll
        for (int r = 0; r < 8; ++r) {
            int row = rg + r;
            if (row < nrows) {
                float4 o;
                o.x = acc[r].x + bias.x; o.y = acc[r].y + bias.y;
                o.z = acc[r].z + bias.z; o.w = acc[r].w + bias.w;
                size_t grow = (size_t)(row0 + row);
                if (m == 0) {
                    *(float4*)(q + grow * HID + jg) = o;
                } else {
                    unsigned int d0 = pack_bf2(o.x, o.y);
                    unsigned int d1 = pack_bf2(o.z, o.w);
                    unsigned int* dst = (m == 1 ? kbf : vbf) + grow * 64 + (jg >> 1);
                    *(uint2*)dst = make_uint2(d0, d1);
                }
            }
        }
    }
}

// ---------------- kernel 5: out = A @ Wo + bo, in-place on A ----------------
__global__ __launch_bounds__(256) void out_gemm_kernel(
    float* __restrict__ A, const float* __restrict__ W, const float* __restrict__ bias) {
    __shared__ float as[64 * HID];
    int row0 = blockIdx.x * 64;
    int nrows = N_NODES - row0; if (nrows > 64) nrows = 64;
    for (int t = threadIdx.x; t < nrows * HID; t += 256) as[t] = A[row0 * HID + t];
    __syncthreads();
    int jg = (threadIdx.x & 31) * 4;
    int rg = (threadIdx.x >> 5) * 8;
    float4 acc[8];
    #pragma unroll
    for (int r = 0; r < 8; ++r) acc[r] = make_float4(0.f, 0.f, 0.f, 0.f);
    for (int i = 0; i < HID; i += 4) {
        float4 w0 = *(const float4*)(W + (i + 0) * HID + jg);
        float4 w1 = *(const float4*)(W + (i + 1) * HID + jg);
        float4 w2 = *(const float4*)(W + (i + 2) * HID + jg);
        float4 w3 = *(const float4*)(W + (i + 3) * HID + jg);
        #pragma unroll
        for (int r = 0; r < 8; ++r) {
            float4 a = *(const float4*)(&as[(rg + r) * HID + i]);
            acc[r].x += a.x * w0.x + a.y * w1.x + a.z * w2.x + a.w * w3.x;
            acc[r].y += a.x * w0.y + a.y * w1.y + a.z * w2.y + a.w * w3.y;
            acc[r].z += a.x * w0.z + a.y * w1.z + a.z * w2.z + a.w * w3.z;
            acc[r].w += a.x * w0.w + a.y * w1.w + a.z * w2.w + a.w * w3.w;
        }
    }
    float4 b = *(const float4*)(bias + jg);
    #pragma unroll
    for (int r = 0; r < 8; ++r) {
        int row = rg + r;
        if (row < nrows) {
            float4 o;
            o.x = acc[r].x + b.x; o.y = acc[r].y + b.y;
            o.z = acc[r].z + b.z; o.w = acc[r].w + b.w;
            *(float4*)(A + (size_t)(row0 + row) * HID + jg) = o;
        }
    }
}

// ---------------- CSR build ----------------
__global__ void count_kernel(const int* __restrict__ ei, int* __restrict__ counts) {
    int e = blockIdx.x * 256 + threadIdx.x;
    if (e < N_EDGES) atomicAdd(&counts[ei[N_EDGES + e]], 1);
}

// hierarchical scan: 1024 elems per block
__global__ __launch_bounds__(256) void scan1_kernel(const int* __restrict__ counts,
                                                    int* __restrict__ row_start,
                                                    int* __restrict__ bsums) {
    __shared__ int wsum[4];
    int b = blockIdx.x, tid = threadIdx.x, lane = tid & 63, w = tid >> 6;
    int i0 = b * 1024 + tid * 4;
    int x0 = (i0 + 0 < N_NODES) ? counts[i0 + 0] : 0;
    int x1 = (i0 + 1 < N_NODES) ? counts[i0 + 1] : 0;
    int x2 = (i0 + 2 < N_NODES) ? counts[i0 + 2] : 0;
    int x3 = (i0 + 3 < N_NODES) ? counts[i0 + 3] : 0;
    int t = x0 + x1 + x2 + x3;
    int val = t;
    #pragma unroll
    for (int off = 1; off < 64; off <<= 1) {
        int y = __shfl_up(val, off);
        if (lane >= off) val += y;
    }
    if (lane == 63) wsum[w] = val;
    __syncthreads();
    int wo = 0;
    if (w > 0) wo += wsum[0];
    if (w > 1) wo += wsum[1];
    if (w > 2) wo += wsum[2];
    int excl = wo + val - t;
    if (i0 + 0 < N_NODES) row_start[i0 + 0] = excl;
    if (i0 + 1 < N_NODES) row_start[i0 + 1] = excl + x0;
    if (i0 + 2 < N_NODES) row_start[i0 + 2] = excl + x0 + x1;
    if (i0 + 3 < N_NODES) row_start[i0 + 3] = excl + x0 + x1 + x2;
    if (tid == 255) bsums[b] = wo + val;
}

__global__ void scan2_kernel(int* __restrict__ bsums, int nblocks) {
    int lane = threadIdx.x;
    int x = (lane < nblocks) ? bsums[lane] : 0;
    int val = x;
    #pragma unroll
    for (int off = 1; off < 64; off <<= 1) {
        int y = __shfl_up(val, off);
        if (lane >= off) val += y;
    }
    if (lane < nblocks) bsums[lane] = val - x;  // exclusive
}

__global__ __launch_bounds__(256) void scan3_kernel(int* __restrict__ row_start,
                                                    const int* __restrict__ bsums) {
    int b = blockIdx.x;
    int off = bsums[b];
    int i0 = b * 1024 + threadIdx.x * 4;
    if (i0 + 3 < N_NODES) {
        int4* p = (int4*)(row_start + i0);
        int4 v = *p;
        v.x += off; v.y += off; v.z += off; v.w += off;
        *p = v;
    } else {
        for (int j = 0; j < 4; ++j)
            if (i0 + j < N_NODES) row_start[i0 + j] += off;
    }
    if (b == 0 && threadIdx.x == 0) row_start[N_NODES] = N_EDGES;
}

__global__ void scatter_kernel(const int* __restrict__ ei, const int* __restrict__ et,
                               const int* __restrict__ row_start, int* __restrict__ cursor,
                               unsigned int* __restrict__ csr) {
    int e = blockIdx.x * 256 + threadIdx.x;
    if (e < N_EDGES) {
        int dst = ei[N_EDGES + e];
        int src = ei[e];
        int pos = atomicAdd(&cursor[dst], 1);
        csr[row_start[dst] + pos] = ((unsigned int)et[e] << 18) | (unsigned int)src;
    }
}

// ---------------- wave-per-node attention: bf16 k/v, LDS scores, fused sum+acc ----------------
__global__ __launch_bounds__(256) void attn_kernel(
    const float* __restrict__ q, const unsigned int* __restrict__ kbf,
    const unsigned int* __restrict__ vbf, const float* __restrict__ rel,
    const int* __restrict__ row_start, const unsigned int* __restrict__ csr,
    float* __restrict__ gscores, float* __restrict__ out) {
    __shared__ float sls[4][CAP * 8];  // 12 KB
    int slot = threadIdx.x >> 6;
    int node = blockIdx.x * 4 + slot;
    int lane = threadIdx.x & 63;
    int h = lane & 7;
    int rs = row_start[node];
    int deg = row_start[node + 1] - rs;
    float* sbuf = sls[slot];

    const float4* qp = (const float4*)(q + (size_t)node * HID + h * HDIM);
    float4 q0 = qp[0], q1 = qp[1], q2 = qp[2], q3 = qp[3];

    // Phase A: scores -> LDS (or global overflow), running max clamped at 0
    float smax = 0.0f;
    for (int base = 0; base < deg; base += 8) {
        int el = base + (lane >> 3);
        if (el < deg) {
            unsigned int pk = csr[rs + el];
            int src = pk & 0x3FFFF;
            int etv = (int)(pk >> 18);
            const uint4* kp = (const uint4*)(kbf + (size_t)src * 64 + h * 8);
            uint4 ka = kp[0], kb = kp[1];
            const float4* rp = (const float4*)(rel + (size_t)etv * HID + h * HDIM);
            float4 r0 = rp[0], r1 = rp[1], r2 = rp[2], r3 = rp[3];
            float s = q0.x * (bf_lo(ka.x) + r0.x) + q0.y * (bf_hi(ka.x) + r0.y)
                    + q0.z * (bf_lo(ka.y) + r0.z) + q0.w * (bf_hi(ka.y) + r0.w)
                    + q1.x * (bf_lo(ka.z) + r1.x) + q1.y * (bf_hi(ka.z) + r1.y)
                    + q1.z * (bf_lo(ka.w) + r1.z) + q1.w * (bf_hi(ka.w) + r1.w)
                    + q2.x * (bf_lo(kb.x) + r2.x) + q2.y * (bf_hi(kb.x) + r2.y)
                    + q2.z * (bf_lo(kb.y) + r2.z) + q2.w * (bf_hi(kb.y) + r2.w)
                    + q3.x * (bf_lo(kb.z) + r3.x) + q3.y * (bf_hi(kb.z) + r3.y)
                    + q3.z * (bf_lo(kb.w) + r3.z) + q3.w * (bf_hi(kb.w) + r3.w);
            s *= 0.25f;  // / sqrt(16)
            if (el < CAP) sbuf[el * 8 + h] = s;
            else gscores[(size_t)(rs + el) * 8 + h] = s;
            smax = fmaxf(smax, s);
        }
    }
    #pragma unroll
    for (int off = 8; off < 64; off <<= 1) smax = fmaxf(smax, __shfl_xor(smax, off));

    __syncthreads();  // LDS + overflow-global stores visible before re-read

    // Phase B+C fused: unnormalized accumulate, normalize at the end.
    // lane owns output dims {2*lane, 2*lane+1}; their head = lane>>3.
    int hd = lane >> 3;
    float ssum = 0.0f;
    float accx = 0.0f, accy = 0.0f;
    for (int base = 0; base < deg; base += 8) {
        int el = base + (lane >> 3);
        float p = 0.0f;
        int src = 0;
        if (el < deg) {
            unsigned int pk = csr[rs + el];
            src = pk & 0x3FFFF;
            float s = (el < CAP) ? sbuf[el * 8 + h] : gscores[(size_t)(rs + el) * 8 + h];
            p = __expf(s - smax);
            ssum += p;
        }
        int cnt = deg - base; if (cnt > 8) cnt = 8;
        for (int j = 0; j < cnt; ++j) {
            int   sj = __shfl(src, j * 8);
            float pj = __shfl(p, j * 8 + hd);
            unsigned int vp = vbf[(size_t)sj * 64 + lane];
            accx += pj * bf_lo(vp);
            accy += pj * bf_hi(vp);
        }
    }
    #pragma unroll
    for (int off = 8; off < 64; off <<= 1) ssum += __shfl_xor(ssum, off);
    float inv = 1.0f / (__shfl(ssum, hd) + 1e-8f);
    *(float2*)(out + (size_t)node * HID + 2 * lane) = make_float2(accx * inv, accy * inv);
}

extern "C" void kernel_launch(void* const* d_in, const int* in_sizes, int n_in,
                              void* d_out, int out_size, void* d_ws, size_t ws_size,
                              hipStream_t stream) {
    const float* nf    = (const float*)d_in[0];
    const float* query = (const float*)d_in[1];
    const float* rel   = (const float*)d_in[2];
    const float* Wq    = (const float*)d_in[3];
    const float* bq    = (const float*)d_in[4];
    const float* Wk    = (const float*)d_in[5];
    const float* bk    = (const float*)d_in[6];
    const float* Wv    = (const float*)d_in[7];
    const float* bv    = (const float*)d_in[8];
    const float* Wo    = (const float*)d_in[9];
    const float* bo    = (const float*)d_in[10];
    const int*   ei    = (const int*)d_in[11];
    const int*   et    = (const int*)d_in[12];
    float* out = (float*)d_out;

    char* ws = (char*)d_ws;
    float* q            = (float*)ws;        ws += (size_t)N_NODES * HID * 4;
    unsigned int* kbf   = (unsigned int*)ws; ws += (size_t)N_NODES * 64 * 4;
    unsigned int* vbf   = (unsigned int*)ws; ws += (size_t)N_NODES * 64 * 4;
    float* gscores      = (float*)ws;        ws += (size_t)N_EDGES * HEADS * 4;
    float* bqe          = (float*)ws;        ws += 128 * 4;
    float* bke          = (float*)ws;        ws += 128 * 4;
    int* row_start      = (int*)ws;          ws += (size_t)(N_NODES + 4) * 4;
    int* counts         = (int*)ws;          ws += (size_t)N_NODES * 4;
    int* cursor         = (int*)ws;          ws += (size_t)N_NODES * 4;
    int* bsums          = (int*)ws;          ws += 64 * 4;
    unsigned int* csr   = (unsigned int*)ws; ws += (size_t)N_EDGES * 4;

    const int SCAN_BLOCKS = (N_NODES + 1023) / 1024;  // 49

    hipMemsetAsync(counts, 0, (size_t)N_NODES * 4, stream);
    hipMemsetAsync(cursor, 0, (size_t)N_NODES * 4, stream);

    bias_fold_kernel<<<1, 128, 0, stream>>>(query, Wq, bq, Wk, bk, bqe, bke);
    qkv_kernel<<<(N_NODES + 63) / 64, 256, 0, stream>>>(nf, Wq, Wk, Wv, bqe, bke, bv, q, kbf, vbf);
    count_kernel<<<(N_EDGES + 255) / 256, 256, 0, stream>>>(ei, counts);
    scan1_kernel<<<SCAN_BLOCKS, 256, 0, stream>>>(counts, row_start, bsums);
    scan2_kernel<<<1, 64, 0, stream>>>(bsums, SCAN_BLOCKS);
    scan3_kernel<<<SCAN_BLOCKS, 256, 0, stream>>>(row_start, bsums);
    scatter_kernel<<<(N_EDGES + 255) / 256, 256, 0, stream>>>(ei, et, row_start, cursor, csr);
    attn_kernel<<<N_NODES / 4, 256, 0, stream>>>(q, kbf, vbf, rel, row_start, csr, gscores, out);
    out_gemm_kernel<<<(N_NODES + 63) / 64, 256, 0, stream>>>(out, Wo, bo);
}

// Round 3
// 381.292 us; speedup vs baseline: 1.3614x; 1.1419x over previous
//
#include <hip/hip_runtime.h>
#include <math.h>

#define N_NODES 50000
#define N_EDGES 800000
#define HID 128
#define HEADS 8
#define HDIM 16
#define CAP 96  // per-node edges kept in LDS; Poisson(16) max deg ~45, global fallback beyond

typedef __attribute__((ext_vector_type(8))) short short8;
typedef __attribute__((ext_vector_type(4))) float floatx4;

__device__ __forceinline__ float bf_lo(unsigned int d) { return __uint_as_float(d << 16); }
__device__ __forceinline__ float bf_hi(unsigned int d) { return __uint_as_float(d & 0xFFFF0000u); }
__device__ __forceinline__ unsigned short f2bf(float f) {
    unsigned int u = __float_as_uint(f);
    u = (u + 0x7FFFu + ((u >> 16) & 1u)) >> 16;  // RNE
    return (unsigned short)u;
}

// ---------------- kernel 0: fold query into q/k biases ----------------
__global__ void bias_fold_kernel(const float* __restrict__ query,
                                 const float* __restrict__ Wq, const float* __restrict__ bq,
                                 const float* __restrict__ Wk, const float* __restrict__ bk,
                                 float* __restrict__ bqe, float* __restrict__ bke) {
    int j = threadIdx.x;  // 128 threads
    float aq = bq[j], ak = bk[j];
    for (int i = 0; i < HID; ++i) {
        float qv = query[i];
        aq += qv * Wq[(HID + i) * HID + j];
        ak += qv * Wk[(HID + i) * HID + j];
    }
    bqe[j] = aq;
    bke[j] = ak;
}

// ---------------- weight transpose + bf16 convert: Wt[m][n][k] = W_m[k][n] ----------------
__global__ __launch_bounds__(256) void conv_w_kernel(
    const float* __restrict__ Wq, const float* __restrict__ Wk, const float* __restrict__ Wv,
    unsigned short* __restrict__ Wt) {
    int idx = blockIdx.x * 256 + threadIdx.x;  // 3*128*128 = 49152
    if (idx >= 3 * HID * HID) return;
    int m = idx >> 14;
    int rem = idx & 16383;
    int n = rem >> 7, k = rem & 127;
    const float* W = (m == 0) ? Wq : (m == 1) ? Wk : Wv;
    Wt[idx] = f2bf(W[k * HID + n]);  // Wq/Wk: rows 0..127 only (query part folded into bias)
}

// ---------------- QKV via MFMA: q fp32 out, k/v bf16 out ----------------
// 64 rows/block, 4 waves; wave w owns rows [w*16,w*16+16), all 8 col-tiles, 3 matrices.
__global__ __launch_bounds__(256) void qkv_mfma_kernel(
    const float* __restrict__ nf, const unsigned short* __restrict__ Wt,
    const float* __restrict__ bqe, const float* __restrict__ bke, const float* __restrict__ bv,
    float* __restrict__ q, unsigned short* __restrict__ kb16, unsigned short* __restrict__ vb16) {
    int row0 = blockIdx.x * 64;
    int wave = threadIdx.x >> 6;
    int lane = threadIdx.x & 63;
    int col  = lane & 15;   // A-row within tile / C-col within tile
    int quad = lane >> 4;   // k-subrange selector; C-row group

    // A fragments: lane holds A[m=col][k=kk*32+quad*8+j], fp32->bf16 on the fly
    int arow = row0 + wave * 16 + col;
    int asafe = (arow < N_NODES) ? arow : (N_NODES - 1);
    short8 afr[4];
    #pragma unroll
    for (int kk = 0; kk < 4; ++kk) {
        const float4* ap = (const float4*)(nf + (size_t)asafe * HID + kk * 32 + quad * 8);
        float4 a0 = ap[0], a1 = ap[1];
        short8 f;
        f[0] = (short)f2bf(a0.x); f[1] = (short)f2bf(a0.y);
        f[2] = (short)f2bf(a0.z); f[3] = (short)f2bf(a0.w);
        f[4] = (short)f2bf(a1.x); f[5] = (short)f2bf(a1.y);
        f[6] = (short)f2bf(a1.z); f[7] = (short)f2bf(a1.w);
        afr[kk] = f;
    }

    const float* biases[3] = {bqe, bke, bv};
    #pragma unroll
    for (int m = 0; m < 3; ++m) {
        const unsigned short* W = Wt + (size_t)m * HID * HID;
        floatx4 acc[8];
        #pragma unroll
        for (int n = 0; n < 8; ++n) {
            float b = biases[m][n * 16 + col];
            acc[n] = (floatx4){b, b, b, b};
        }
        #pragma unroll
        for (int kk = 0; kk < 4; ++kk) {
            #pragma unroll
            for (int n = 0; n < 8; ++n) {
                short8 bfr = *(const short8*)(W + (size_t)(n * 16 + col) * HID + kk * 32 + quad * 8);
                acc[n] = __builtin_amdgcn_mfma_f32_16x16x32_bf16(afr[kk], bfr, acc[n], 0, 0, 0);
            }
        }
        // C layout: col=lane&15, row=quad*4+i
        #pragma unroll
        for (int n = 0; n < 8; ++n) {
            #pragma unroll
            for (int i = 0; i < 4; ++i) {
                int r = row0 + wave * 16 + quad * 4 + i;
                if (r < N_NODES) {
                    int c = n * 16 + col;
                    if (m == 0)      q[(size_t)r * HID + c] = acc[n][i];
                    else if (m == 1) kb16[(size_t)r * HID + c] = f2bf(acc[n][i]);
                    else             vb16[(size_t)r * HID + c] = f2bf(acc[n][i]);
                }
            }
        }
    }
}

// ---------------- out = A @ Wo + bo, in-place on A (fp32, precision-safe) ----------------
__global__ __launch_bounds__(256) void out_gemm_kernel(
    float* __restrict__ A, const float* __restrict__ W, const float* __restrict__ bias) {
    __shared__ float as[64 * HID];
    int row0 = blockIdx.x * 64;
    int nrows = N_NODES - row0; if (nrows > 64) nrows = 64;
    for (int t = threadIdx.x; t < nrows * HID; t += 256) as[t] = A[row0 * HID + t];
    __syncthreads();
    int jg = (threadIdx.x & 31) * 4;
    int rg = (threadIdx.x >> 5) * 8;
    float4 acc[8];
    #pragma unroll
    for (int r = 0; r < 8; ++r) acc[r] = make_float4(0.f, 0.f, 0.f, 0.f);
    for (int i = 0; i < HID; i += 4) {
        float4 w0 = *(const float4*)(W + (i + 0) * HID + jg);
        float4 w1 = *(const float4*)(W + (i + 1) * HID + jg);
        float4 w2 = *(const float4*)(W + (i + 2) * HID + jg);
        float4 w3 = *(const float4*)(W + (i + 3) * HID + jg);
        #pragma unroll
        for (int r = 0; r < 8; ++r) {
            float4 a = *(const float4*)(&as[(rg + r) * HID + i]);
            acc[r].x += a.x * w0.x + a.y * w1.x + a.z * w2.x + a.w * w3.x;
            acc[r].y += a.x * w0.y + a.y * w1.y + a.z * w2.y + a.w * w3.y;
            acc[r].z += a.x * w0.z + a.y * w1.z + a.z * w2.z + a.w * w3.z;
            acc[r].w += a.x * w0.w + a.y * w1.w + a.z * w2.w + a.w * w3.w;
        }
    }
    float4 b = *(const float4*)(bias + jg);
    #pragma unroll
    for (int r = 0; r < 8; ++r) {
        int row = rg + r;
        if (row < nrows) {
            float4 o;
            o.x = acc[r].x + b.x; o.y = acc[r].y + b.y;
            o.z = acc[r].z + b.z; o.w = acc[r].w + b.w;
            *(float4*)(A + (size_t)(row0 + row) * HID + jg) = o;
        }
    }
}

// ---------------- CSR build ----------------
__global__ void count_kernel(const int* __restrict__ ei, int* __restrict__ counts) {
    int e = blockIdx.x * 256 + threadIdx.x;
    if (e < N_EDGES) atomicAdd(&counts[ei[N_EDGES + e]], 1);
}

__global__ __launch_bounds__(256) void scan1_kernel(const int* __restrict__ counts,
                                                    int* __restrict__ row_start,
                                                    int* __restrict__ bsums) {
    __shared__ int wsum[4];
    int b = blockIdx.x, tid = threadIdx.x, lane = tid & 63, w = tid >> 6;
    int i0 = b * 1024 + tid * 4;
    int x0 = (i0 + 0 < N_NODES) ? counts[i0 + 0] : 0;
    int x1 = (i0 + 1 < N_NODES) ? counts[i0 + 1] : 0;
    int x2 = (i0 + 2 < N_NODES) ? counts[i0 + 2] : 0;
    int x3 = (i0 + 3 < N_NODES) ? counts[i0 + 3] : 0;
    int t = x0 + x1 + x2 + x3;
    int val = t;
    #pragma unroll
    for (int off = 1; off < 64; off <<= 1) {
        int y = __shfl_up(val, off);
        if (lane >= off) val += y;
    }
    if (lane == 63) wsum[w] = val;
    __syncthreads();
    int wo = 0;
    if (w > 0) wo += wsum[0];
    if (w > 1) wo += wsum[1];
    if (w > 2) wo += wsum[2];
    int excl = wo + val - t;
    if (i0 + 0 < N_NODES) row_start[i0 + 0] = excl;
    if (i0 + 1 < N_NODES) row_start[i0 + 1] = excl + x0;
    if (i0 + 2 < N_NODES) row_start[i0 + 2] = excl + x0 + x1;
    if (i0 + 3 < N_NODES) row_start[i0 + 3] = excl + x0 + x1 + x2;
    if (tid == 255) bsums[b] = wo + val;
}

__global__ void scan2_kernel(int* __restrict__ bsums, int nblocks) {
    int lane = threadIdx.x;
    int x = (lane < nblocks) ? bsums[lane] : 0;
    int val = x;
    #pragma unroll
    for (int off = 1; off < 64; off <<= 1) {
        int y = __shfl_up(val, off);
        if (lane >= off) val += y;
    }
    if (lane < nblocks) bsums[lane] = val - x;  // exclusive
}

__global__ __launch_bounds__(256) void scan3_kernel(int* __restrict__ row_start,
                                                    const int* __restrict__ bsums) {
    int b = blockIdx.x;
    int off = bsums[b];
    int i0 = b * 1024 + threadIdx.x * 4;
    if (i0 + 3 < N_NODES) {
        int4* p = (int4*)(row_start + i0);
        int4 v = *p;
        v.x += off; v.y += off; v.z += off; v.w += off;
        *p = v;
    } else {
        for (int j = 0; j < 4; ++j)
            if (i0 + j < N_NODES) row_start[i0 + j] += off;
    }
    if (b == 0 && threadIdx.x == 0) row_start[N_NODES] = N_EDGES;
}

__global__ void scatter_kernel(const int* __restrict__ ei, const int* __restrict__ et,
                               const int* __restrict__ row_start, int* __restrict__ cursor,
                               unsigned int* __restrict__ csr) {
    int e = blockIdx.x * 256 + threadIdx.x;
    if (e < N_EDGES) {
        int dst = ei[N_EDGES + e];
        int src = ei[e];
        int pos = atomicAdd(&cursor[dst], 1);
        csr[row_start[dst] + pos] = ((unsigned int)et[e] << 18) | (unsigned int)src;
    }
}

// ---------------- wave-per-node attention: bf16 k/v, LDS scores, fused sum+acc ----------------
__global__ __launch_bounds__(256) void attn_kernel(
    const float* __restrict__ q, const unsigned int* __restrict__ kbf,
    const unsigned int* __restrict__ vbf, const float* __restrict__ rel,
    const int* __restrict__ row_start, const unsigned int* __restrict__ csr,
    float* __restrict__ gscores, float* __restrict__ out) {
    __shared__ float sls[4][CAP * 8];  // 12 KB
    int slot = threadIdx.x >> 6;
    int node = blockIdx.x * 4 + slot;
    int lane = threadIdx.x & 63;
    int h = lane & 7;
    int rs = row_start[node];
    int deg = row_start[node + 1] - rs;
    float* sbuf = sls[slot];

    const float4* qp = (const float4*)(q + (size_t)node * HID + h * HDIM);
    float4 q0 = qp[0], q1 = qp[1], q2 = qp[2], q3 = qp[3];

    // Phase A: scores -> LDS (global overflow), running max clamped at 0
    float smax = 0.0f;
    for (int base = 0; base < deg; base += 8) {
        int el = base + (lane >> 3);
        if (el < deg) {
            unsigned int pk = csr[rs + el];
            int src = pk & 0x3FFFF;
            int etv = (int)(pk >> 18);
            const uint4* kp = (const uint4*)(kbf + (size_t)src * 64 + h * 8);
            uint4 ka = kp[0], kb = kp[1];
            const float4* rp = (const float4*)(rel + (size_t)etv * HID + h * HDIM);
            float4 r0 = rp[0], r1 = rp[1], r2 = rp[2], r3 = rp[3];
            float s = q0.x * (bf_lo(ka.x) + r0.x) + q0.y * (bf_hi(ka.x) + r0.y)
                    + q0.z * (bf_lo(ka.y) + r0.z) + q0.w * (bf_hi(ka.y) + r0.w)
                    + q1.x * (bf_lo(ka.z) + r1.x) + q1.y * (bf_hi(ka.z) + r1.y)
                    + q1.z * (bf_lo(ka.w) + r1.z) + q1.w * (bf_hi(ka.w) + r1.w)
                    + q2.x * (bf_lo(kb.x) + r2.x) + q2.y * (bf_hi(kb.x) + r2.y)
                    + q2.z * (bf_lo(kb.y) + r2.z) + q2.w * (bf_hi(kb.y) + r2.w)
                    + q3.x * (bf_lo(kb.z) + r3.x) + q3.y * (bf_hi(kb.z) + r3.y)
                    + q3.z * (bf_lo(kb.w) + r3.z) + q3.w * (bf_hi(kb.w) + r3.w);
            s *= 0.25f;  // / sqrt(16)
            if (el < CAP) sbuf[el * 8 + h] = s;
            else gscores[(size_t)(rs + el) * 8 + h] = s;
            smax = fmaxf(smax, s);
        }
    }
    #pragma unroll
    for (int off = 8; off < 64; off <<= 1) smax = fmaxf(smax, __shfl_xor(smax, off));

    __syncthreads();

    // Phase B+C fused: unnormalized accumulate, normalize at end.
    int hd = lane >> 3;
    float ssum = 0.0f;
    float accx = 0.0f, accy = 0.0f;
    for (int base = 0; base < deg; base += 8) {
        int el = base + (lane >> 3);
        float p = 0.0f;
        int src = 0;
        if (el < deg) {
            unsigned int pk = csr[rs + el];
            src = pk & 0x3FFFF;
            float s = (el < CAP) ? sbuf[el * 8 + h] : gscores[(size_t)(rs + el) * 8 + h];
            p = __expf(s - smax);
            ssum += p;
        }
        int cnt = deg - base; if (cnt > 8) cnt = 8;
        for (int j = 0; j < cnt; ++j) {
            int   sj = __shfl(src, j * 8);
            float pj = __shfl(p, j * 8 + hd);
            unsigned int vp = vbf[(size_t)sj * 64 + lane];
            accx += pj * bf_lo(vp);
            accy += pj * bf_hi(vp);
        }
    }
    #pragma unroll
    for (int off = 8; off < 64; off <<= 1) ssum += __shfl_xor(ssum, off);
    float inv = 1.0f / (__shfl(ssum, hd) + 1e-8f);
    *(float2*)(out + (size_t)node * HID + 2 * lane) = make_float2(accx * inv, accy * inv);
}

extern "C" void kernel_launch(void* const* d_in, const int* in_sizes, int n_in,
                              void* d_out, int out_size, void* d_ws, size_t ws_size,
                              hipStream_t stream) {
    const float* nf    = (const float*)d_in[0];
    const float* query = (const float*)d_in[1];
    const float* rel   = (const float*)d_in[2];
    const float* Wq    = (const float*)d_in[3];
    const float* bq    = (const float*)d_in[4];
    const float* Wk    = (const float*)d_in[5];
    const float* bk    = (const float*)d_in[6];
    const float* Wv    = (const float*)d_in[7];
    const float* bv    = (const float*)d_in[8];
    const float* Wo    = (const float*)d_in[9];
    const float* bo    = (const float*)d_in[10];
    const int*   ei    = (const int*)d_in[11];
    const int*   et    = (const int*)d_in[12];
    float* out = (float*)d_out;

    char* ws = (char*)d_ws;
    float* q            = (float*)ws;        ws += (size_t)N_NODES * HID * 4;
    unsigned int* kbf   = (unsigned int*)ws; ws += (size_t)N_NODES * 64 * 4;
    unsigned int* vbf   = (unsigned int*)ws; ws += (size_t)N_NODES * 64 * 4;
    float* gscores      = (float*)ws;        ws += (size_t)N_EDGES * HEADS * 4;
    float* bqe          = (float*)ws;        ws += 128 * 4;
    float* bke          = (float*)ws;        ws += 128 * 4;
    int* row_start      = (int*)ws;          ws += (size_t)(N_NODES + 4) * 4;
    int* counts         = (int*)ws;          ws += (size_t)N_NODES * 4;
    int* cursor         = (int*)ws;          ws += (size_t)N_NODES * 4;
    int* bsums          = (int*)ws;          ws += 64 * 4;
    unsigned int* csr   = (unsigned int*)ws; ws += (size_t)N_EDGES * 4;
    unsigned short* Wt  = (unsigned short*)ws; ws += (size_t)3 * HID * HID * 2;

    const int SCAN_BLOCKS = (N_NODES + 1023) / 1024;  // 49

    hipMemsetAsync(counts, 0, (size_t)N_NODES * 4, stream);
    hipMemsetAsync(cursor, 0, (size_t)N_NODES * 4, stream);

    bias_fold_kernel<<<1, 128, 0, stream>>>(query, Wq, bq, Wk, bk, bqe, bke);
    conv_w_kernel<<<(3 * HID * HID + 255) / 256, 256, 0, stream>>>(Wq, Wk, Wv, Wt);
    qkv_mfma_kernel<<<(N_NODES + 63) / 64, 256, 0, stream>>>(
        nf, Wt, bqe, bke, bv, q, (unsigned short*)kbf, (unsigned short*)vbf);
    count_kernel<<<(N_EDGES + 255) / 256, 256, 0, stream>>>(ei, counts);
    scan1_kernel<<<SCAN_BLOCKS, 256, 0, stream>>>(counts, row_start, bsums);
    scan2_kernel<<<1, 64, 0, stream>>>(bsums, SCAN_BLOCKS);
    scan3_kernel<<<SCAN_BLOCKS, 256, 0, stream>>>(row_start, bsums);
    scatter_kernel<<<(N_EDGES + 255) / 256, 256, 0, stream>>>(ei, et, row_start, cursor, csr);
    attn_kernel<<<N_NODES / 4, 256, 0, stream>>>(q, kbf, vbf, rel, row_start, csr, gscores, out);
    out_gemm_kernel<<<(N_NODES + 63) / 64, 256, 0, stream>>>(out, Wo, bo);
}

// Round 4
// 306.970 us; speedup vs baseline: 1.6910x; 1.2421x over previous
//
#include <hip/hip_runtime.h>
#include <math.h>

#define N_NODES 50000
#define N_EDGES 800000
#define HID 128
#define HEADS 8
#define HDIM 16
#define CAP 96  // per-node edges kept in LDS; Poisson(16) max deg ~45, global fallback beyond

typedef __attribute__((ext_vector_type(8))) short short8;
typedef __attribute__((ext_vector_type(4))) float floatx4;

__device__ __forceinline__ float bf_lo(unsigned int d) { return __uint_as_float(d << 16); }
__device__ __forceinline__ float bf_hi(unsigned int d) { return __uint_as_float(d & 0xFFFF0000u); }
__device__ __forceinline__ unsigned short f2bf(float f) {
    unsigned int u = __float_as_uint(f);
    u = (u + 0x7FFFu + ((u >> 16) & 1u)) >> 16;  // RNE
    return (unsigned short)u;
}
__device__ __forceinline__ unsigned int pack_bf2(float a, float b) {
    return (unsigned int)f2bf(a) | ((unsigned int)f2bf(b) << 16);
}

// ---------------- prep: weight transpose->bf16 (Wq,Wk,Wv,Wo) + query bias fold ----------------
// Wt[m][n][k] = W_m[k][n]; block 256 does the bias fold.
__global__ __launch_bounds__(256) void prep_kernel(
    const float* __restrict__ query,
    const float* __restrict__ Wq, const float* __restrict__ bq,
    const float* __restrict__ Wk, const float* __restrict__ bk,
    const float* __restrict__ Wv, const float* __restrict__ Wo,
    unsigned short* __restrict__ Wt, float* __restrict__ bqe, float* __restrict__ bke) {
    if (blockIdx.x == 256) {
        int j = threadIdx.x;
        if (j < HID) {
            float aq = bq[j], ak = bk[j];
            for (int i = 0; i < HID; ++i) {
                float qv = query[i];
                aq += qv * Wq[(HID + i) * HID + j];
                ak += qv * Wk[(HID + i) * HID + j];
            }
            bqe[j] = aq;
            bke[j] = ak;
        }
        return;
    }
    int idx = blockIdx.x * 256 + threadIdx.x;  // 4*128*128 = 65536
    int m = idx >> 14;
    int rem = idx & 16383;
    int n = rem >> 7, k = rem & 127;
    const float* W = (m == 0) ? Wq : (m == 1) ? Wk : (m == 2) ? Wv : Wo;
    Wt[idx] = f2bf(W[k * HID + n]);  // Wq/Wk: rows 0..127 only (query part folded into bias)
}

// ---------------- QKV via MFMA: q fp32 out, k/v bf16 out ----------------
__global__ __launch_bounds__(256) void qkv_mfma_kernel(
    const float* __restrict__ nf, const unsigned short* __restrict__ Wt,
    const float* __restrict__ bqe, const float* __restrict__ bke, const float* __restrict__ bv,
    float* __restrict__ q, unsigned short* __restrict__ kb16, unsigned short* __restrict__ vb16) {
    int row0 = blockIdx.x * 64;
    int wave = threadIdx.x >> 6;
    int lane = threadIdx.x & 63;
    int col  = lane & 15;
    int quad = lane >> 4;

    int arow = row0 + wave * 16 + col;
    int asafe = (arow < N_NODES) ? arow : (N_NODES - 1);
    short8 afr[4];
    #pragma unroll
    for (int kk = 0; kk < 4; ++kk) {
        const float4* ap = (const float4*)(nf + (size_t)asafe * HID + kk * 32 + quad * 8);
        float4 a0 = ap[0], a1 = ap[1];
        short8 f;
        f[0] = (short)f2bf(a0.x); f[1] = (short)f2bf(a0.y);
        f[2] = (short)f2bf(a0.z); f[3] = (short)f2bf(a0.w);
        f[4] = (short)f2bf(a1.x); f[5] = (short)f2bf(a1.y);
        f[6] = (short)f2bf(a1.z); f[7] = (short)f2bf(a1.w);
        afr[kk] = f;
    }

    const float* biases[3] = {bqe, bke, bv};
    #pragma unroll
    for (int m = 0; m < 3; ++m) {
        const unsigned short* W = Wt + (size_t)m * HID * HID;
        floatx4 acc[8];
        #pragma unroll
        for (int n = 0; n < 8; ++n) {
            float b = biases[m][n * 16 + col];
            acc[n] = (floatx4){b, b, b, b};
        }
        #pragma unroll
        for (int kk = 0; kk < 4; ++kk) {
            #pragma unroll
            for (int n = 0; n < 8; ++n) {
                short8 bfr = *(const short8*)(W + (size_t)(n * 16 + col) * HID + kk * 32 + quad * 8);
                acc[n] = __builtin_amdgcn_mfma_f32_16x16x32_bf16(afr[kk], bfr, acc[n], 0, 0, 0);
            }
        }
        #pragma unroll
        for (int n = 0; n < 8; ++n) {
            #pragma unroll
            for (int i = 0; i < 4; ++i) {
                int r = row0 + wave * 16 + quad * 4 + i;
                if (r < N_NODES) {
                    int c = n * 16 + col;
                    if (m == 0)      q[(size_t)r * HID + c] = acc[n][i];
                    else if (m == 1) kb16[(size_t)r * HID + c] = f2bf(acc[n][i]);
                    else             vb16[(size_t)r * HID + c] = f2bf(acc[n][i]);
                }
            }
        }
    }
}

// ---------------- out = Abf16 @ Wo + bo via MFMA, writes fp32 d_out ----------------
__global__ __launch_bounds__(256) void out_mfma_kernel(
    const unsigned short* __restrict__ abuf, const unsigned short* __restrict__ Wot,
    const float* __restrict__ bo, float* __restrict__ out) {
    int row0 = blockIdx.x * 64;
    int wave = threadIdx.x >> 6;
    int lane = threadIdx.x & 63;
    int col  = lane & 15;
    int quad = lane >> 4;

    int arow = row0 + wave * 16 + col;
    int asafe = (arow < N_NODES) ? arow : (N_NODES - 1);
    short8 afr[4];
    #pragma unroll
    for (int kk = 0; kk < 4; ++kk)
        afr[kk] = *(const short8*)(abuf + (size_t)asafe * HID + kk * 32 + quad * 8);

    floatx4 acc[8];
    #pragma unroll
    for (int n = 0; n < 8; ++n) {
        float b = bo[n * 16 + col];
        acc[n] = (floatx4){b, b, b, b};
    }
    #pragma unroll
    for (int kk = 0; kk < 4; ++kk) {
        #pragma unroll
        for (int n = 0; n < 8; ++n) {
            short8 bfr = *(const short8*)(Wot + (size_t)(n * 16 + col) * HID + kk * 32 + quad * 8);
            acc[n] = __builtin_amdgcn_mfma_f32_16x16x32_bf16(afr[kk], bfr, acc[n], 0, 0, 0);
        }
    }
    #pragma unroll
    for (int n = 0; n < 8; ++n) {
        #pragma unroll
        for (int i = 0; i < 4; ++i) {
            int r = row0 + wave * 16 + quad * 4 + i;
            if (r < N_NODES) out[(size_t)r * HID + n * 16 + col] = acc[n][i];
        }
    }
}

// ---------------- CSR build ----------------
// count records each edge's within-node slot -> scatter needs no atomics.
__global__ void count_kernel(const int* __restrict__ ei, int* __restrict__ counts,
                             int* __restrict__ epos) {
    int e = blockIdx.x * 256 + threadIdx.x;
    if (e < N_EDGES) epos[e] = atomicAdd(&counts[ei[N_EDGES + e]], 1);
}

__global__ __launch_bounds__(256) void scan1_kernel(const int* __restrict__ counts,
                                                    int* __restrict__ row_start,
                                                    int* __restrict__ bsums) {
    __shared__ int wsum[4];
    int b = blockIdx.x, tid = threadIdx.x, lane = tid & 63, w = tid >> 6;
    int i0 = b * 1024 + tid * 4;
    int x0 = (i0 + 0 < N_NODES) ? counts[i0 + 0] : 0;
    int x1 = (i0 + 1 < N_NODES) ? counts[i0 + 1] : 0;
    int x2 = (i0 + 2 < N_NODES) ? counts[i0 + 2] : 0;
    int x3 = (i0 + 3 < N_NODES) ? counts[i0 + 3] : 0;
    int t = x0 + x1 + x2 + x3;
    int val = t;
    #pragma unroll
    for (int off = 1; off < 64; off <<= 1) {
        int y = __shfl_up(val, off);
        if (lane >= off) val += y;
    }
    if (lane == 63) wsum[w] = val;
    __syncthreads();
    int wo = 0;
    if (w > 0) wo += wsum[0];
    if (w > 1) wo += wsum[1];
    if (w > 2) wo += wsum[2];
    int excl = wo + val - t;
    if (i0 + 0 < N_NODES) row_start[i0 + 0] = excl;
    if (i0 + 1 < N_NODES) row_start[i0 + 1] = excl + x0;
    if (i0 + 2 < N_NODES) row_start[i0 + 2] = excl + x0 + x1;
    if (i0 + 3 < N_NODES) row_start[i0 + 3] = excl + x0 + x1 + x2;
    if (tid == 255) bsums[b] = wo + val;
}

__global__ void scan2_kernel(int* __restrict__ bsums, int nblocks) {
    int lane = threadIdx.x;
    int x = (lane < nblocks) ? bsums[lane] : 0;
    int val = x;
    #pragma unroll
    for (int off = 1; off < 64; off <<= 1) {
        int y = __shfl_up(val, off);
        if (lane >= off) val += y;
    }
    if (lane < nblocks) bsums[lane] = val - x;  // exclusive
}

__global__ __launch_bounds__(256) void scan3_kernel(int* __restrict__ row_start,
                                                    const int* __restrict__ bsums) {
    int b = blockIdx.x;
    int off = bsums[b];
    int i0 = b * 1024 + threadIdx.x * 4;
    if (i0 + 3 < N_NODES) {
        int4* p = (int4*)(row_start + i0);
        int4 v = *p;
        v.x += off; v.y += off; v.z += off; v.w += off;
        *p = v;
    } else {
        for (int j = 0; j < 4; ++j)
            if (i0 + j < N_NODES) row_start[i0 + j] += off;
    }
    if (b == 0 && threadIdx.x == 0) row_start[N_NODES] = N_EDGES;
}

__global__ void scatter_kernel(const int* __restrict__ ei, const int* __restrict__ et,
                               const int* __restrict__ row_start, const int* __restrict__ epos,
                               unsigned int* __restrict__ csr) {
    int e = blockIdx.x * 256 + threadIdx.x;
    if (e < N_EDGES) {
        int dst = ei[N_EDGES + e];
        csr[row_start[dst] + epos[e]] = ((unsigned int)et[e] << 18) | (unsigned int)ei[e];
    }
}

// ---------------- wave-per-node attention; writes bf16 A-buffer ----------------
__global__ __launch_bounds__(256) void attn_kernel(
    const float* __restrict__ q, const unsigned int* __restrict__ kbf,
    const unsigned int* __restrict__ vbf, const float* __restrict__ rel,
    const int* __restrict__ row_start, const unsigned int* __restrict__ csr,
    float* __restrict__ gscores, unsigned int* __restrict__ abuf) {
    __shared__ float sls[4][CAP * 8];  // 12 KB
    int slot = threadIdx.x >> 6;
    int node = blockIdx.x * 4 + slot;
    int lane = threadIdx.x & 63;
    int h = lane & 7;
    int rs = row_start[node];
    int deg = row_start[node + 1] - rs;
    float* sbuf = sls[slot];

    const float4* qp = (const float4*)(q + (size_t)node * HID + h * HDIM);
    float4 q0 = qp[0], q1 = qp[1], q2 = qp[2], q3 = qp[3];

    // Phase A: scores -> LDS (global overflow), running max clamped at 0
    float smax = 0.0f;
    for (int base = 0; base < deg; base += 8) {
        int el = base + (lane >> 3);
        if (el < deg) {
            unsigned int pk = csr[rs + el];
            int src = pk & 0x3FFFF;
            int etv = (int)(pk >> 18);
            const uint4* kp = (const uint4*)(kbf + (size_t)src * 64 + h * 8);
            uint4 ka = kp[0], kb = kp[1];
            const float4* rp = (const float4*)(rel + (size_t)etv * HID + h * HDIM);
            float4 r0 = rp[0], r1 = rp[1], r2 = rp[2], r3 = rp[3];
            float s = q0.x * (bf_lo(ka.x) + r0.x) + q0.y * (bf_hi(ka.x) + r0.y)
                    + q0.z * (bf_lo(ka.y) + r0.z) + q0.w * (bf_hi(ka.y) + r0.w)
                    + q1.x * (bf_lo(ka.z) + r1.x) + q1.y * (bf_hi(ka.z) + r1.y)
                    + q1.z * (bf_lo(ka.w) + r1.z) + q1.w * (bf_hi(ka.w) + r1.w)
                    + q2.x * (bf_lo(kb.x) + r2.x) + q2.y * (bf_hi(kb.x) + r2.y)
                    + q2.z * (bf_lo(kb.y) + r2.z) + q2.w * (bf_hi(kb.y) + r2.w)
                    + q3.x * (bf_lo(kb.z) + r3.x) + q3.y * (bf_hi(kb.z) + r3.y)
                    + q3.z * (bf_lo(kb.w) + r3.z) + q3.w * (bf_hi(kb.w) + r3.w);
            s *= 0.25f;  // / sqrt(16)
            if (el < CAP) sbuf[el * 8 + h] = s;
            else gscores[(size_t)(rs + el) * 8 + h] = s;
            smax = fmaxf(smax, s);
        }
    }
    #pragma unroll
    for (int off = 8; off < 64; off <<= 1) smax = fmaxf(smax, __shfl_xor(smax, off));

    __syncthreads();

    // Phase B+C fused, FIXED inner trip count (8) so the compiler unrolls and
    // keeps 8 v-row loads in flight; masked lanes contribute p=0.
    int hd = lane >> 3;
    float ssum = 0.0f;
    float accx = 0.0f, accy = 0.0f;
    for (int base = 0; base < deg; base += 8) {
        int el = base + (lane >> 3);
        float p = 0.0f;
        int src = 0;
        if (el < deg) {
            unsigned int pk = csr[rs + el];
            src = pk & 0x3FFFF;
            float s = (el < CAP) ? sbuf[el * 8 + h] : gscores[(size_t)(rs + el) * 8 + h];
            p = __expf(s - smax);
            ssum += p;
        }
        #pragma unroll
        for (int j = 0; j < 8; ++j) {
            int   sj = __shfl(src, j * 8);
            float pj = __shfl(p, j * 8 + hd);
            unsigned int vp = vbf[(size_t)sj * 64 + lane];
            accx += pj * bf_lo(vp);
            accy += pj * bf_hi(vp);
        }
    }
    #pragma unroll
    for (int off = 8; off < 64; off <<= 1) ssum += __shfl_xor(ssum, off);
    float inv = 1.0f / (__shfl(ssum, hd) + 1e-8f);
    abuf[(size_t)node * 64 + lane] = pack_bf2(accx * inv, accy * inv);
}

extern "C" void kernel_launch(void* const* d_in, const int* in_sizes, int n_in,
                              void* d_out, int out_size, void* d_ws, size_t ws_size,
                              hipStream_t stream) {
    const float* nf    = (const float*)d_in[0];
    const float* query = (const float*)d_in[1];
    const float* rel   = (const float*)d_in[2];
    const float* Wq    = (const float*)d_in[3];
    const float* bq    = (const float*)d_in[4];
    const float* Wk    = (const float*)d_in[5];
    const float* bk    = (const float*)d_in[6];
    const float* Wv    = (const float*)d_in[7];
    const float* bv    = (const float*)d_in[8];
    const float* Wo    = (const float*)d_in[9];
    const float* bo    = (const float*)d_in[10];
    const int*   ei    = (const int*)d_in[11];
    const int*   et    = (const int*)d_in[12];
    float* out = (float*)d_out;

    char* ws = (char*)d_ws;
    float* q            = (float*)ws;        ws += (size_t)N_NODES * HID * 4;
    unsigned int* kbf   = (unsigned int*)ws; ws += (size_t)N_NODES * 64 * 4;
    unsigned int* vbf   = (unsigned int*)ws; ws += (size_t)N_NODES * 64 * 4;
    float* gscores      = (float*)ws;        ws += (size_t)N_EDGES * HEADS * 4;
    unsigned int* abuf  = (unsigned int*)ws; ws += (size_t)N_NODES * 64 * 4;
    float* bqe          = (float*)ws;        ws += 128 * 4;
    float* bke          = (float*)ws;        ws += 128 * 4;
    int* row_start      = (int*)ws;          ws += (size_t)(N_NODES + 4) * 4;
    int* counts         = (int*)ws;          ws += (size_t)N_NODES * 4;
    int* epos           = (int*)ws;          ws += (size_t)N_EDGES * 4;
    int* bsums          = (int*)ws;          ws += 64 * 4;
    unsigned int* csr   = (unsigned int*)ws; ws += (size_t)N_EDGES * 4;
    unsigned short* Wt  = (unsigned short*)ws; ws += (size_t)4 * HID * HID * 2;

    const int SCAN_BLOCKS = (N_NODES + 1023) / 1024;  // 49

    hipMemsetAsync(counts, 0, (size_t)N_NODES * 4, stream);

    prep_kernel<<<257, 256, 0, stream>>>(query, Wq, bq, Wk, bk, Wv, Wo, Wt, bqe, bke);
    qkv_mfma_kernel<<<(N_NODES + 63) / 64, 256, 0, stream>>>(
        nf, Wt, bqe, bke, bv, q, (unsigned short*)kbf, (unsigned short*)vbf);
    count_kernel<<<(N_EDGES + 255) / 256, 256, 0, stream>>>(ei, counts, epos);
    scan1_kernel<<<SCAN_BLOCKS, 256, 0, stream>>>(counts, row_start, bsums);
    scan2_kernel<<<1, 64, 0, stream>>>(bsums, SCAN_BLOCKS);
    scan3_kernel<<<SCAN_BLOCKS, 256, 0, stream>>>(row_start, bsums);
    scatter_kernel<<<(N_EDGES + 255) / 256, 256, 0, stream>>>(ei, et, row_start, epos, csr);
    attn_kernel<<<N_NODES / 4, 256, 0, stream>>>(q, kbf, vbf, rel, row_start, csr, gscores, abuf);
    out_mfma_kernel<<<(N_NODES + 63) / 64, 256, 0, stream>>>(
        (const unsigned short*)abuf, Wt + (size_t)3 * HID * HID, bo, out);
}

// Round 5
// 287.016 us; speedup vs baseline: 1.8085x; 1.0695x over previous
//
#include <hip/hip_runtime.h>
#include <math.h>

#define N_NODES 50000
#define N_EDGES 800000
#define HID 128
#define HEADS 8
#define HDIM 16

typedef __attribute__((ext_vector_type(8))) short short8;
typedef __attribute__((ext_vector_type(4))) float floatx4;

#if defined(__has_builtin)
#if __has_builtin(__builtin_amdgcn_fdot2_f32_bf16)
#define HAVE_DOT2 1
#endif
#endif
#ifndef HAVE_DOT2
#define HAVE_DOT2 0
#endif

#if HAVE_DOT2
typedef __attribute__((ext_vector_type(2))) __bf16 bf16x2;
__device__ __forceinline__ float dot2acc(unsigned int a, unsigned int b, float c) {
    return __builtin_amdgcn_fdot2_f32_bf16(__builtin_bit_cast(bf16x2, a),
                                           __builtin_bit_cast(bf16x2, b), c, false);
}
#endif

__device__ __forceinline__ float bf_lo(unsigned int d) { return __uint_as_float(d << 16); }
__device__ __forceinline__ float bf_hi(unsigned int d) { return __uint_as_float(d & 0xFFFF0000u); }
__device__ __forceinline__ unsigned short f2bf(float f) {
    unsigned int u = __float_as_uint(f);
    u = (u + 0x7FFFu + ((u >> 16) & 1u)) >> 16;  // RNE
    return (unsigned short)u;
}
__device__ __forceinline__ unsigned int pack_bf2(float a, float b) {
    return (unsigned int)f2bf(a) | ((unsigned int)f2bf(b) << 16);
}

// ---------------- prep: weight transpose->bf16 (Wq,Wk,Wv,Wo), rel->bf16,
// zero counts, query bias fold ----------------
__global__ __launch_bounds__(256) void prep_kernel(
    const float* __restrict__ query, const float* __restrict__ rel,
    const float* __restrict__ Wq, const float* __restrict__ bq,
    const float* __restrict__ Wk, const float* __restrict__ bk,
    const float* __restrict__ Wv, const float* __restrict__ Wo,
    unsigned short* __restrict__ Wt, unsigned short* __restrict__ relbf,
    int* __restrict__ counts, float* __restrict__ bqe, float* __restrict__ bke) {
    if (blockIdx.x == 256) {
        int j = threadIdx.x;
        if (j < HID) {
            float aq = bq[j], ak = bk[j];
            for (int i = 0; i < HID; ++i) {
                float qv = query[i];
                aq += qv * Wq[(HID + i) * HID + j];
                ak += qv * Wk[(HID + i) * HID + j];
            }
            bqe[j] = aq;
            bke[j] = ak;
        }
        return;
    }
    int idx = blockIdx.x * 256 + threadIdx.x;  // < 65536
    if (idx < N_NODES) counts[idx] = 0;
    if (idx < 64 * HID) relbf[idx] = f2bf(rel[idx]);
    int m = idx >> 14;
    int rem = idx & 16383;
    int n = rem >> 7, k = rem & 127;
    const float* W = (m == 0) ? Wq : (m == 1) ? Wk : (m == 2) ? Wv : Wo;
    Wt[idx] = f2bf(W[k * HID + n]);  // Wq/Wk: rows 0..127 only (query part folded into bias)
}

// ---------------- QKV via MFMA: q bf16, k/v interleaved bf16 ----------------
__global__ __launch_bounds__(256) void qkv_mfma_kernel(
    const float* __restrict__ nf, const unsigned short* __restrict__ Wt,
    const float* __restrict__ bqe, const float* __restrict__ bke, const float* __restrict__ bv,
    unsigned short* __restrict__ qb16, unsigned short* __restrict__ kv16) {
    int row0 = blockIdx.x * 64;
    int wave = threadIdx.x >> 6;
    int lane = threadIdx.x & 63;
    int col  = lane & 15;
    int quad = lane >> 4;

    int arow = row0 + wave * 16 + col;
    int asafe = (arow < N_NODES) ? arow : (N_NODES - 1);
    short8 afr[4];
    #pragma unroll
    for (int kk = 0; kk < 4; ++kk) {
        const float4* ap = (const float4*)(nf + (size_t)asafe * HID + kk * 32 + quad * 8);
        float4 a0 = ap[0], a1 = ap[1];
        short8 f;
        f[0] = (short)f2bf(a0.x); f[1] = (short)f2bf(a0.y);
        f[2] = (short)f2bf(a0.z); f[3] = (short)f2bf(a0.w);
        f[4] = (short)f2bf(a1.x); f[5] = (short)f2bf(a1.y);
        f[6] = (short)f2bf(a1.z); f[7] = (short)f2bf(a1.w);
        afr[kk] = f;
    }

    const float* biases[3] = {bqe, bke, bv};
    #pragma unroll
    for (int m = 0; m < 3; ++m) {
        const unsigned short* W = Wt + (size_t)m * HID * HID;
        floatx4 acc[8];
        #pragma unroll
        for (int n = 0; n < 8; ++n) {
            float b = biases[m][n * 16 + col];
            acc[n] = (floatx4){b, b, b, b};
        }
        #pragma unroll
        for (int kk = 0; kk < 4; ++kk) {
            #pragma unroll
            for (int n = 0; n < 8; ++n) {
                short8 bfr = *(const short8*)(W + (size_t)(n * 16 + col) * HID + kk * 32 + quad * 8);
                acc[n] = __builtin_amdgcn_mfma_f32_16x16x32_bf16(afr[kk], bfr, acc[n], 0, 0, 0);
            }
        }
        #pragma unroll
        for (int n = 0; n < 8; ++n) {
            #pragma unroll
            for (int i = 0; i < 4; ++i) {
                int r = row0 + wave * 16 + quad * 4 + i;
                if (r < N_NODES) {
                    int c = n * 16 + col;
                    if (m == 0)      qb16[(size_t)r * HID + c] = f2bf(acc[n][i]);
                    else if (m == 1) kv16[(size_t)r * 256 + c] = f2bf(acc[n][i]);
                    else             kv16[(size_t)r * 256 + 128 + c] = f2bf(acc[n][i]);
                }
            }
        }
    }
}

// ---------------- out = Abf16 @ Wo + bo via MFMA, writes fp32 d_out ----------------
__global__ __launch_bounds__(256) void out_mfma_kernel(
    const unsigned short* __restrict__ abuf, const unsigned short* __restrict__ Wot,
    const float* __restrict__ bo, float* __restrict__ out) {
    int row0 = blockIdx.x * 64;
    int wave = threadIdx.x >> 6;
    int lane = threadIdx.x & 63;
    int col  = lane & 15;
    int quad = lane >> 4;

    int arow = row0 + wave * 16 + col;
    int asafe = (arow < N_NODES) ? arow : (N_NODES - 1);
    short8 afr[4];
    #pragma unroll
    for (int kk = 0; kk < 4; ++kk)
        afr[kk] = *(const short8*)(abuf + (size_t)asafe * HID + kk * 32 + quad * 8);

    floatx4 acc[8];
    #pragma unroll
    for (int n = 0; n < 8; ++n) {
        float b = bo[n * 16 + col];
        acc[n] = (floatx4){b, b, b, b};
    }
    #pragma unroll
    for (int kk = 0; kk < 4; ++kk) {
        #pragma unroll
        for (int n = 0; n < 8; ++n) {
            short8 bfr = *(const short8*)(Wot + (size_t)(n * 16 + col) * HID + kk * 32 + quad * 8);
            acc[n] = __builtin_amdgcn_mfma_f32_16x16x32_bf16(afr[kk], bfr, acc[n], 0, 0, 0);
        }
    }
    #pragma unroll
    for (int n = 0; n < 8; ++n) {
        #pragma unroll
        for (int i = 0; i < 4; ++i) {
            int r = row0 + wave * 16 + quad * 4 + i;
            if (r < N_NODES) out[(size_t)r * HID + n * 16 + col] = acc[n][i];
        }
    }
}

// ---------------- CSR build ----------------
__global__ void count_kernel(const int* __restrict__ ei, int* __restrict__ counts,
                             int* __restrict__ epos) {
    int e = blockIdx.x * 256 + threadIdx.x;
    if (e < N_EDGES) epos[e] = atomicAdd(&counts[ei[N_EDGES + e]], 1);
}

__global__ __launch_bounds__(256) void scan1_kernel(const int* __restrict__ counts,
                                                    int* __restrict__ row_start,
                                                    int* __restrict__ bsums) {
    __shared__ int wsum[4];
    int b = blockIdx.x, tid = threadIdx.x, lane = tid & 63, w = tid >> 6;
    int i0 = b * 1024 + tid * 4;
    int x0 = (i0 + 0 < N_NODES) ? counts[i0 + 0] : 0;
    int x1 = (i0 + 1 < N_NODES) ? counts[i0 + 1] : 0;
    int x2 = (i0 + 2 < N_NODES) ? counts[i0 + 2] : 0;
    int x3 = (i0 + 3 < N_NODES) ? counts[i0 + 3] : 0;
    int t = x0 + x1 + x2 + x3;
    int val = t;
    #pragma unroll
    for (int off = 1; off < 64; off <<= 1) {
        int y = __shfl_up(val, off);
        if (lane >= off) val += y;
    }
    if (lane == 63) wsum[w] = val;
    __syncthreads();
    int wo = 0;
    if (w > 0) wo += wsum[0];
    if (w > 1) wo += wsum[1];
    if (w > 2) wo += wsum[2];
    int excl = wo + val - t;
    if (i0 + 0 < N_NODES) row_start[i0 + 0] = excl;
    if (i0 + 1 < N_NODES) row_start[i0 + 1] = excl + x0;
    if (i0 + 2 < N_NODES) row_start[i0 + 2] = excl + x0 + x1;
    if (i0 + 3 < N_NODES) row_start[i0 + 3] = excl + x0 + x1 + x2;
    if (tid == 255) bsums[b] = wo + val;
}

__global__ void scan2_kernel(int* __restrict__ bsums, int nblocks) {
    int lane = threadIdx.x;
    int x = (lane < nblocks) ? bsums[lane] : 0;
    int val = x;
    #pragma unroll
    for (int off = 1; off < 64; off <<= 1) {
        int y = __shfl_up(val, off);
        if (lane >= off) val += y;
    }
    if (lane < nblocks) bsums[lane] = val - x;  // exclusive
}

__global__ __launch_bounds__(256) void scan3_kernel(int* __restrict__ row_start,
                                                    const int* __restrict__ bsums) {
    int b = blockIdx.x;
    int off = bsums[b];
    int i0 = b * 1024 + threadIdx.x * 4;
    if (i0 + 3 < N_NODES) {
        int4* p = (int4*)(row_start + i0);
        int4 v = *p;
        v.x += off; v.y += off; v.z += off; v.w += off;
        *p = v;
    } else {
        for (int j = 0; j < 4; ++j)
            if (i0 + j < N_NODES) row_start[i0 + j] += off;
    }
    if (b == 0 && threadIdx.x == 0) row_start[N_NODES] = N_EDGES;
}

__global__ void scatter_kernel(const int* __restrict__ ei, const int* __restrict__ et,
                               const int* __restrict__ row_start, const int* __restrict__ epos,
                               unsigned int* __restrict__ csr) {
    int e = blockIdx.x * 256 + threadIdx.x;
    if (e < N_EDGES) {
        int dst = ei[N_EDGES + e];
        csr[row_start[dst] + epos[e]] = ((unsigned int)et[e] << 18) | (unsigned int)ei[e];
    }
}

// ---------------- single-pass wave-per-node attention ----------------
// No max subtraction (ref's m>=0 clamp makes 1e-8 negligible; exp(s) can't
// overflow for ~N(0,1) scores). No LDS, no barrier: one streaming pass.
__global__ __launch_bounds__(256) void attn_kernel(
    const unsigned int* __restrict__ qb, const unsigned int* __restrict__ kvu,
    const float* __restrict__ rel, const unsigned int* __restrict__ relu,
    const int* __restrict__ row_start, const unsigned int* __restrict__ csr,
    unsigned int* __restrict__ abuf) {
    int node = blockIdx.x * 4 + (threadIdx.x >> 6);
    int lane = threadIdx.x & 63;
    int h = lane & 7;
    int hd = lane >> 3;
    int rs = row_start[node];
    int deg = row_start[node + 1] - rs;

    const uint4* qp = (const uint4*)(qb + (size_t)node * 64 + h * 8);
    uint4 qa = qp[0], qc = qp[1];
#if !HAVE_DOT2
    float qf0 = bf_lo(qa.x), qf1 = bf_hi(qa.x), qf2 = bf_lo(qa.y), qf3 = bf_hi(qa.y);
    float qf4 = bf_lo(qa.z), qf5 = bf_hi(qa.z), qf6 = bf_lo(qa.w), qf7 = bf_hi(qa.w);
    float qf8 = bf_lo(qc.x), qf9 = bf_hi(qc.x), qf10 = bf_lo(qc.y), qf11 = bf_hi(qc.y);
    float qf12 = bf_lo(qc.z), qf13 = bf_hi(qc.z), qf14 = bf_lo(qc.w), qf15 = bf_hi(qc.w);
#endif

    float ssum = 0.0f, accx = 0.0f, accy = 0.0f;
    for (int base = 0; base < deg; base += 8) {
        int el = base + (lane >> 3);
        float w = 0.0f;
        int src = 0;
        if (el < deg) {
            unsigned int pk = csr[rs + el];
            src = pk & 0x3FFFF;
            int etv = (int)(pk >> 18);
            const uint4* kp = (const uint4*)(kvu + (size_t)src * 128 + h * 8);
            uint4 ka = kp[0], kb = kp[1];
            float s;
#if HAVE_DOT2
            const uint4* rp = (const uint4*)(relu + (size_t)etv * 64 + h * 8);
            uint4 ra = rp[0], rb = rp[1];
            s = dot2acc(qa.x, ka.x, 0.0f);
            s = dot2acc(qa.y, ka.y, s); s = dot2acc(qa.z, ka.z, s); s = dot2acc(qa.w, ka.w, s);
            s = dot2acc(qc.x, kb.x, s); s = dot2acc(qc.y, kb.y, s);
            s = dot2acc(qc.z, kb.z, s); s = dot2acc(qc.w, kb.w, s);
            s = dot2acc(qa.x, ra.x, s); s = dot2acc(qa.y, ra.y, s);
            s = dot2acc(qa.z, ra.z, s); s = dot2acc(qa.w, ra.w, s);
            s = dot2acc(qc.x, rb.x, s); s = dot2acc(qc.y, rb.y, s);
            s = dot2acc(qc.z, rb.z, s); s = dot2acc(qc.w, rb.w, s);
#else
            const float4* rp = (const float4*)(rel + (size_t)etv * HID + h * HDIM);
            float4 r0 = rp[0], r1 = rp[1], r2 = rp[2], r3 = rp[3];
            s = qf0 * (bf_lo(ka.x) + r0.x) + qf1 * (bf_hi(ka.x) + r0.y)
              + qf2 * (bf_lo(ka.y) + r0.z) + qf3 * (bf_hi(ka.y) + r0.w)
              + qf4 * (bf_lo(ka.z) + r1.x) + qf5 * (bf_hi(ka.z) + r1.y)
              + qf6 * (bf_lo(ka.w) + r1.z) + qf7 * (bf_hi(ka.w) + r1.w)
              + qf8 * (bf_lo(kb.x) + r2.x) + qf9 * (bf_hi(kb.x) + r2.y)
              + qf10 * (bf_lo(kb.y) + r2.z) + qf11 * (bf_hi(kb.y) + r2.w)
              + qf12 * (bf_lo(kb.z) + r3.x) + qf13 * (bf_hi(kb.z) + r3.y)
              + qf14 * (bf_lo(kb.w) + r3.z) + qf15 * (bf_hi(kb.w) + r3.w);
#endif
            w = __expf(s * 0.25f);  // / sqrt(16)
            ssum += w;
        }
        #pragma unroll
        for (int j = 0; j < 8; ++j) {
            int   sj = __shfl(src, j * 8);
            float wj = __shfl(w, j * 8 + hd);
            unsigned int vp = kvu[(size_t)sj * 128 + 64 + lane];
            accx += wj * bf_lo(vp);
            accy += wj * bf_hi(vp);
        }
    }
    #pragma unroll
    for (int off = 8; off < 64; off <<= 1) ssum += __shfl_xor(ssum, off);
    float inv = 1.0f / (__shfl(ssum, hd) + 1e-8f);
    abuf[(size_t)node * 64 + lane] = pack_bf2(accx * inv, accy * inv);
}

extern "C" void kernel_launch(void* const* d_in, const int* in_sizes, int n_in,
                              void* d_out, int out_size, void* d_ws, size_t ws_size,
                              hipStream_t stream) {
    const float* nf    = (const float*)d_in[0];
    const float* query = (const float*)d_in[1];
    const float* rel   = (const float*)d_in[2];
    const float* Wq    = (const float*)d_in[3];
    const float* bq    = (const float*)d_in[4];
    const float* Wk    = (const float*)d_in[5];
    const float* bk    = (const float*)d_in[6];
    const float* Wv    = (const float*)d_in[7];
    const float* bv    = (const float*)d_in[8];
    const float* Wo    = (const float*)d_in[9];
    const float* bo    = (const float*)d_in[10];
    const int*   ei    = (const int*)d_in[11];
    const int*   et    = (const int*)d_in[12];
    float* out = (float*)d_out;

    char* ws = (char*)d_ws;
    unsigned short* qb16 = (unsigned short*)ws; ws += (size_t)N_NODES * HID * 2;
    unsigned short* kv16 = (unsigned short*)ws; ws += (size_t)N_NODES * 256 * 2;
    unsigned int* abuf   = (unsigned int*)ws;   ws += (size_t)N_NODES * 64 * 4;
    float* bqe           = (float*)ws;          ws += 128 * 4;
    float* bke           = (float*)ws;          ws += 128 * 4;
    int* row_start       = (int*)ws;            ws += (size_t)(N_NODES + 4) * 4;
    int* counts          = (int*)ws;            ws += (size_t)N_NODES * 4;
    int* epos            = (int*)ws;            ws += (size_t)N_EDGES * 4;
    int* bsums           = (int*)ws;            ws += 64 * 4;
    unsigned int* csr    = (unsigned int*)ws;   ws += (size_t)N_EDGES * 4;
    unsigned short* Wt   = (unsigned short*)ws; ws += (size_t)4 * HID * HID * 2;
    unsigned short* relbf = (unsigned short*)ws; ws += (size_t)64 * HID * 2;

    const int SCAN_BLOCKS = (N_NODES + 1023) / 1024;  // 49

    prep_kernel<<<257, 256, 0, stream>>>(query, rel, Wq, bq, Wk, bk, Wv, Wo,
                                         Wt, relbf, counts, bqe, bke);
    qkv_mfma_kernel<<<(N_NODES + 63) / 64, 256, 0, stream>>>(
        nf, Wt, bqe, bke, bv, qb16, kv16);
    count_kernel<<<(N_EDGES + 255) / 256, 256, 0, stream>>>(ei, counts, epos);
    scan1_kernel<<<SCAN_BLOCKS, 256, 0, stream>>>(counts, row_start, bsums);
    scan2_kernel<<<1, 64, 0, stream>>>(bsums, SCAN_BLOCKS);
    scan3_kernel<<<SCAN_BLOCKS, 256, 0, stream>>>(row_start, bsums);
    scatter_kernel<<<(N_EDGES + 255) / 256, 256, 0, stream>>>(ei, et, row_start, epos, csr);
    attn_kernel<<<N_NODES / 4, 256, 0, stream>>>(
        (const unsigned int*)qb16, (const unsigned int*)kv16, rel,
        (const unsigned int*)relbf, row_start, csr, abuf);
    out_mfma_kernel<<<(N_NODES + 63) / 64, 256, 0, stream>>>(
        (const unsigned short*)abuf, Wt + (size_t)3 * HID * HID, bo, out);
}

// Round 6
// 262.049 us; speedup vs baseline: 1.9808x; 1.0953x over previous
//
#include <hip/hip_runtime.h>
#include <math.h>

#define N_NODES 50000
#define N_EDGES 800000
#define HID 128
#define HEADS 8
#define HDIM 16

typedef __attribute__((ext_vector_type(8))) short short8;
typedef __attribute__((ext_vector_type(4))) float floatx4;

#if defined(__has_builtin)
#if __has_builtin(__builtin_amdgcn_fdot2_f32_bf16)
#define HAVE_DOT2 1
#endif
#endif
#ifndef HAVE_DOT2
#define HAVE_DOT2 0
#endif

#if HAVE_DOT2
typedef __attribute__((ext_vector_type(2))) __bf16 bf16x2;
__device__ __forceinline__ float dot2acc(unsigned int a, unsigned int b, float c) {
    return __builtin_amdgcn_fdot2_f32_bf16(__builtin_bit_cast(bf16x2, a),
                                           __builtin_bit_cast(bf16x2, b), c, false);
}
#endif

__device__ __forceinline__ float bf_lo(unsigned int d) { return __uint_as_float(d << 16); }
__device__ __forceinline__ float bf_hi(unsigned int d) { return __uint_as_float(d & 0xFFFF0000u); }
__device__ __forceinline__ unsigned short f2bf(float f) {
    unsigned int u = __float_as_uint(f);
    u = (u + 0x7FFFu + ((u >> 16) & 1u)) >> 16;  // RNE
    return (unsigned short)u;
}
__device__ __forceinline__ unsigned int pack_bf2(float a, float b) {
    return (unsigned int)f2bf(a) | ((unsigned int)f2bf(b) << 16);
}

// ---------------- prep: weight transpose->bf16 (Wq,Wk,Wv,Wo), rel->bf16,
// zero counts, query bias fold ----------------
__global__ __launch_bounds__(256) void prep_kernel(
    const float* __restrict__ query, const float* __restrict__ rel,
    const float* __restrict__ Wq, const float* __restrict__ bq,
    const float* __restrict__ Wk, const float* __restrict__ bk,
    const float* __restrict__ Wv, const float* __restrict__ Wo,
    unsigned short* __restrict__ Wt, unsigned short* __restrict__ relbf,
    int* __restrict__ counts, float* __restrict__ bqe, float* __restrict__ bke) {
    if (blockIdx.x == 256) {
        int j = threadIdx.x;
        if (j < HID) {
            float aq = bq[j], ak = bk[j];
            for (int i = 0; i < HID; ++i) {
                float qv = query[i];
                aq += qv * Wq[(HID + i) * HID + j];
                ak += qv * Wk[(HID + i) * HID + j];
            }
            bqe[j] = aq;
            bke[j] = ak;
        }
        return;
    }
    int idx = blockIdx.x * 256 + threadIdx.x;  // < 65536
    if (idx < N_NODES) counts[idx] = 0;
    if (idx < 64 * HID) relbf[idx] = f2bf(rel[idx]);
    int m = idx >> 14;
    int rem = idx & 16383;
    int n = rem >> 7, k = rem & 127;
    const float* W = (m == 0) ? Wq : (m == 1) ? Wk : (m == 2) ? Wv : Wo;
    Wt[idx] = f2bf(W[k * HID + n]);  // Wq/Wk: rows 0..127 only (query part folded into bias)
}

// ---------------- QKV via MFMA: q bf16, k/v interleaved bf16 ----------------
// Waves split the N dimension: each wave owns all 4 row-tiles (64 rows) and
// 2 col-tiles -> each B-fragment load feeds 4 independent MFMAs (ILP), and
// B-load count is 4x lower than the M-split layout.
__global__ __launch_bounds__(256) void qkv_mfma_kernel(
    const float* __restrict__ nf, const unsigned short* __restrict__ Wt,
    const float* __restrict__ bqe, const float* __restrict__ bke, const float* __restrict__ bv,
    unsigned short* __restrict__ qb16, unsigned short* __restrict__ kv16) {
    int row0 = blockIdx.x * 64;
    int wave = threadIdx.x >> 6;   // n-range selector
    int lane = threadIdx.x & 63;
    int col  = lane & 15;
    int quad = lane >> 4;

    // A fragments for all 4 row-tiles, reused across 3 matrices x 2 n-tiles.
    short8 afr[4][4];
    #pragma unroll
    for (int t = 0; t < 4; ++t) {
        int arow = row0 + t * 16 + col;
        int asafe = (arow < N_NODES) ? arow : (N_NODES - 1);
        #pragma unroll
        for (int kk = 0; kk < 4; ++kk) {
            const float4* ap = (const float4*)(nf + (size_t)asafe * HID + kk * 32 + quad * 8);
            float4 a0 = ap[0], a1 = ap[1];
            short8 f;
            f[0] = (short)f2bf(a0.x); f[1] = (short)f2bf(a0.y);
            f[2] = (short)f2bf(a0.z); f[3] = (short)f2bf(a0.w);
            f[4] = (short)f2bf(a1.x); f[5] = (short)f2bf(a1.y);
            f[6] = (short)f2bf(a1.z); f[7] = (short)f2bf(a1.w);
            afr[t][kk] = f;
        }
    }

    const float* biases[3] = {bqe, bke, bv};
    #pragma unroll
    for (int m = 0; m < 3; ++m) {
        const unsigned short* W = Wt + (size_t)m * HID * HID;
        #pragma unroll
        for (int nn = 0; nn < 2; ++nn) {
            int n = wave * 2 + nn;
            float b = biases[m][n * 16 + col];
            floatx4 acc[4];
            #pragma unroll
            for (int t = 0; t < 4; ++t) acc[t] = (floatx4){b, b, b, b};
            short8 bfr[4];
            #pragma unroll
            for (int kk = 0; kk < 4; ++kk)
                bfr[kk] = *(const short8*)(W + (size_t)(n * 16 + col) * HID + kk * 32 + quad * 8);
            #pragma unroll
            for (int kk = 0; kk < 4; ++kk)
                #pragma unroll
                for (int t = 0; t < 4; ++t)
                    acc[t] = __builtin_amdgcn_mfma_f32_16x16x32_bf16(afr[t][kk], bfr[kk], acc[t], 0, 0, 0);
            #pragma unroll
            for (int t = 0; t < 4; ++t) {
                #pragma unroll
                for (int i = 0; i < 4; ++i) {
                    int r = row0 + t * 16 + quad * 4 + i;
                    if (r < N_NODES) {
                        int c = n * 16 + col;
                        if (m == 0)      qb16[(size_t)r * HID + c] = f2bf(acc[t][i]);
                        else if (m == 1) kv16[(size_t)r * 256 + c] = f2bf(acc[t][i]);
                        else             kv16[(size_t)r * 256 + 128 + c] = f2bf(acc[t][i]);
                    }
                }
            }
        }
    }
}

// ---------------- out = Abf16 @ Wo + bo via MFMA (N-split waves), fp32 out ----------------
__global__ __launch_bounds__(256) void out_mfma_kernel(
    const unsigned short* __restrict__ abuf, const unsigned short* __restrict__ Wot,
    const float* __restrict__ bo, float* __restrict__ out) {
    int row0 = blockIdx.x * 64;
    int wave = threadIdx.x >> 6;
    int lane = threadIdx.x & 63;
    int col  = lane & 15;
    int quad = lane >> 4;

    short8 afr[4][4];
    #pragma unroll
    for (int t = 0; t < 4; ++t) {
        int arow = row0 + t * 16 + col;
        int asafe = (arow < N_NODES) ? arow : (N_NODES - 1);
        #pragma unroll
        for (int kk = 0; kk < 4; ++kk)
            afr[t][kk] = *(const short8*)(abuf + (size_t)asafe * HID + kk * 32 + quad * 8);
    }

    #pragma unroll
    for (int nn = 0; nn < 2; ++nn) {
        int n = wave * 2 + nn;
        float b = bo[n * 16 + col];
        floatx4 acc[4];
        #pragma unroll
        for (int t = 0; t < 4; ++t) acc[t] = (floatx4){b, b, b, b};
        short8 bfr[4];
        #pragma unroll
        for (int kk = 0; kk < 4; ++kk)
            bfr[kk] = *(const short8*)(Wot + (size_t)(n * 16 + col) * HID + kk * 32 + quad * 8);
        #pragma unroll
        for (int kk = 0; kk < 4; ++kk)
            #pragma unroll
            for (int t = 0; t < 4; ++t)
                acc[t] = __builtin_amdgcn_mfma_f32_16x16x32_bf16(afr[t][kk], bfr[kk], acc[t], 0, 0, 0);
        #pragma unroll
        for (int t = 0; t < 4; ++t) {
            #pragma unroll
            for (int i = 0; i < 4; ++i) {
                int r = row0 + t * 16 + quad * 4 + i;
                if (r < N_NODES) out[(size_t)r * HID + n * 16 + col] = acc[t][i];
            }
        }
    }
}

// ---------------- CSR build ----------------
__global__ void count_kernel(const int* __restrict__ ei, int* __restrict__ counts,
                             int* __restrict__ epos) {
    int e = blockIdx.x * 256 + threadIdx.x;
    if (e < N_EDGES) epos[e] = atomicAdd(&counts[ei[N_EDGES + e]], 1);
}

__global__ __launch_bounds__(256) void scan1_kernel(const int* __restrict__ counts,
                                                    int* __restrict__ row_start,
                                                    int* __restrict__ bsums) {
    __shared__ int wsum[4];
    int b = blockIdx.x, tid = threadIdx.x, lane = tid & 63, w = tid >> 6;
    int i0 = b * 1024 + tid * 4;
    int x0 = (i0 + 0 < N_NODES) ? counts[i0 + 0] : 0;
    int x1 = (i0 + 1 < N_NODES) ? counts[i0 + 1] : 0;
    int x2 = (i0 + 2 < N_NODES) ? counts[i0 + 2] : 0;
    int x3 = (i0 + 3 < N_NODES) ? counts[i0 + 3] : 0;
    int t = x0 + x1 + x2 + x3;
    int val = t;
    #pragma unroll
    for (int off = 1; off < 64; off <<= 1) {
        int y = __shfl_up(val, off);
        if (lane >= off) val += y;
    }
    if (lane == 63) wsum[w] = val;
    __syncthreads();
    int wo = 0;
    if (w > 0) wo += wsum[0];
    if (w > 1) wo += wsum[1];
    if (w > 2) wo += wsum[2];
    int excl = wo + val - t;
    if (i0 + 0 < N_NODES) row_start[i0 + 0] = excl;
    if (i0 + 1 < N_NODES) row_start[i0 + 1] = excl + x0;
    if (i0 + 2 < N_NODES) row_start[i0 + 2] = excl + x0 + x1;
    if (i0 + 3 < N_NODES) row_start[i0 + 3] = excl + x0 + x1 + x2;
    if (tid == 255) bsums[b] = wo + val;
}

__global__ void scan2_kernel(int* __restrict__ bsums, int nblocks) {
    int lane = threadIdx.x;
    int x = (lane < nblocks) ? bsums[lane] : 0;
    int val = x;
    #pragma unroll
    for (int off = 1; off < 64; off <<= 1) {
        int y = __shfl_up(val, off);
        if (lane >= off) val += y;
    }
    if (lane < nblocks) bsums[lane] = val - x;  // exclusive
}

__global__ __launch_bounds__(256) void scan3_kernel(int* __restrict__ row_start,
                                                    const int* __restrict__ bsums) {
    int b = blockIdx.x;
    int off = bsums[b];
    int i0 = b * 1024 + threadIdx.x * 4;
    if (i0 + 3 < N_NODES) {
        int4* p = (int4*)(row_start + i0);
        int4 v = *p;
        v.x += off; v.y += off; v.z += off; v.w += off;
        *p = v;
    } else {
        for (int j = 0; j < 4; ++j)
            if (i0 + j < N_NODES) row_start[i0 + j] += off;
    }
    if (b == 0 && threadIdx.x == 0) row_start[N_NODES] = N_EDGES;
}

__global__ void scatter_kernel(const int* __restrict__ ei, const int* __restrict__ et,
                               const int* __restrict__ row_start, const int* __restrict__ epos,
                               unsigned int* __restrict__ csr) {
    int e = blockIdx.x * 256 + threadIdx.x;
    if (e < N_EDGES) {
        int dst = ei[N_EDGES + e];
        csr[row_start[dst] + epos[e]] = ((unsigned int)et[e] << 18) | (unsigned int)ei[e];
    }
}

// ---------------- single-pass wave-per-node attention ----------------
__global__ __launch_bounds__(256) void attn_kernel(
    const unsigned int* __restrict__ qb, const unsigned int* __restrict__ kvu,
    const float* __restrict__ rel, const unsigned int* __restrict__ relu,
    const int* __restrict__ row_start, const unsigned int* __restrict__ csr,
    unsigned int* __restrict__ abuf) {
    int node = blockIdx.x * 4 + (threadIdx.x >> 6);
    int lane = threadIdx.x & 63;
    int h = lane & 7;
    int hd = lane >> 3;
    int rs = row_start[node];
    int deg = row_start[node + 1] - rs;

    const uint4* qp = (const uint4*)(qb + (size_t)node * 64 + h * 8);
    uint4 qa = qp[0], qc = qp[1];
#if !HAVE_DOT2
    float qf0 = bf_lo(qa.x), qf1 = bf_hi(qa.x), qf2 = bf_lo(qa.y), qf3 = bf_hi(qa.y);
    float qf4 = bf_lo(qa.z), qf5 = bf_hi(qa.z), qf6 = bf_lo(qa.w), qf7 = bf_hi(qa.w);
    float qf8 = bf_lo(qc.x), qf9 = bf_hi(qc.x), qf10 = bf_lo(qc.y), qf11 = bf_hi(qc.y);
    float qf12 = bf_lo(qc.z), qf13 = bf_hi(qc.z), qf14 = bf_lo(qc.w), qf15 = bf_hi(qc.w);
#endif

    float ssum = 0.0f, accx = 0.0f, accy = 0.0f;
    for (int base = 0; base < deg; base += 8) {
        int el = base + (lane >> 3);
        float w = 0.0f;
        int src = 0;
        if (el < deg) {
            unsigned int pk = csr[rs + el];
            src = pk & 0x3FFFF;
            int etv = (int)(pk >> 18);
            const uint4* kp = (const uint4*)(kvu + (size_t)src * 128 + h * 8);
            uint4 ka = kp[0], kb = kp[1];
            float s;
#if HAVE_DOT2
            const uint4* rp = (const uint4*)(relu + (size_t)etv * 64 + h * 8);
            uint4 ra = rp[0], rb = rp[1];
            s = dot2acc(qa.x, ka.x, 0.0f);
            s = dot2acc(qa.y, ka.y, s); s = dot2acc(qa.z, ka.z, s); s = dot2acc(qa.w, ka.w, s);
            s = dot2acc(qc.x, kb.x, s); s = dot2acc(qc.y, kb.y, s);
            s = dot2acc(qc.z, kb.z, s); s = dot2acc(qc.w, kb.w, s);
            s = dot2acc(qa.x, ra.x, s); s = dot2acc(qa.y, ra.y, s);
            s = dot2acc(qa.z, ra.z, s); s = dot2acc(qa.w, ra.w, s);
            s = dot2acc(qc.x, rb.x, s); s = dot2acc(qc.y, rb.y, s);
            s = dot2acc(qc.z, rb.z, s); s = dot2acc(qc.w, rb.w, s);
#else
            const float4* rp = (const float4*)(rel + (size_t)etv * HID + h * HDIM);
            float4 r0 = rp[0], r1 = rp[1], r2 = rp[2], r3 = rp[3];
            s = qf0 * (bf_lo(ka.x) + r0.x) + qf1 * (bf_hi(ka.x) + r0.y)
              + qf2 * (bf_lo(ka.y) + r0.z) + qf3 * (bf_hi(ka.y) + r0.w)
              + qf4 * (bf_lo(ka.z) + r1.x) + qf5 * (bf_hi(ka.z) + r1.y)
              + qf6 * (bf_lo(ka.w) + r1.z) + qf7 * (bf_hi(ka.w) + r1.w)
              + qf8 * (bf_lo(kb.x) + r2.x) + qf9 * (bf_hi(kb.x) + r2.y)
              + qf10 * (bf_lo(kb.y) + r2.z) + qf11 * (bf_hi(kb.y) + r2.w)
              + qf12 * (bf_lo(kb.z) + r3.x) + qf13 * (bf_hi(kb.z) + r3.y)
              + qf14 * (bf_lo(kb.w) + r3.z) + qf15 * (bf_hi(kb.w) + r3.w);
#endif
            w = __expf(s * 0.25f);  // / sqrt(16)
            ssum += w;
        }
        #pragma unroll
        for (int j = 0; j < 8; ++j) {
            int   sj = __shfl(src, j * 8);
            float wj = __shfl(w, j * 8 + hd);
            unsigned int vp = kvu[(size_t)sj * 128 + 64 + lane];
            accx += wj * bf_lo(vp);
            accy += wj * bf_hi(vp);
        }
    }
    #pragma unroll
    for (int off = 8; off < 64; off <<= 1) ssum += __shfl_xor(ssum, off);
    float inv = 1.0f / (__shfl(ssum, hd) + 1e-8f);
    abuf[(size_t)node * 64 + lane] = pack_bf2(accx * inv, accy * inv);
}

extern "C" void kernel_launch(void* const* d_in, const int* in_sizes, int n_in,
                              void* d_out, int out_size, void* d_ws, size_t ws_size,
                              hipStream_t stream) {
    const float* nf    = (const float*)d_in[0];
    const float* query = (const float*)d_in[1];
    const float* rel   = (const float*)d_in[2];
    const float* Wq    = (const float*)d_in[3];
    const float* bq    = (const float*)d_in[4];
    const float* Wk    = (const float*)d_in[5];
    const float* bk    = (const float*)d_in[6];
    const float* Wv    = (const float*)d_in[7];
    const float* bv    = (const float*)d_in[8];
    const float* Wo    = (const float*)d_in[9];
    const float* bo    = (const float*)d_in[10];
    const int*   ei    = (const int*)d_in[11];
    const int*   et    = (const int*)d_in[12];
    float* out = (float*)d_out;

    char* ws = (char*)d_ws;
    unsigned short* qb16 = (unsigned short*)ws; ws += (size_t)N_NODES * HID * 2;
    unsigned short* kv16 = (unsigned short*)ws; ws += (size_t)N_NODES * 256 * 2;
    unsigned int* abuf   = (unsigned int*)ws;   ws += (size_t)N_NODES * 64 * 4;
    float* bqe           = (float*)ws;          ws += 128 * 4;
    float* bke           = (float*)ws;          ws += 128 * 4;
    int* row_start       = (int*)ws;            ws += (size_t)(N_NODES + 4) * 4;
    int* counts          = (int*)ws;            ws += (size_t)N_NODES * 4;
    int* epos            = (int*)ws;            ws += (size_t)N_EDGES * 4;
    int* bsums           = (int*)ws;            ws += 64 * 4;
    unsigned int* csr    = (unsigned int*)ws;   ws += (size_t)N_EDGES * 4;
    unsigned short* Wt   = (unsigned short*)ws; ws += (size_t)4 * HID * HID * 2;
    unsigned short* relbf = (unsigned short*)ws; ws += (size_t)64 * HID * 2;

    const int SCAN_BLOCKS = (N_NODES + 1023) / 1024;  // 49

    prep_kernel<<<257, 256, 0, stream>>>(query, rel, Wq, bq, Wk, bk, Wv, Wo,
                                         Wt, relbf, counts, bqe, bke);
    qkv_mfma_kernel<<<(N_NODES + 63) / 64, 256, 0, stream>>>(
        nf, Wt, bqe, bke, bv, qb16, kv16);
    count_kernel<<<(N_EDGES + 255) / 256, 256, 0, stream>>>(ei, counts, epos);
    scan1_kernel<<<SCAN_BLOCKS, 256, 0, stream>>>(counts, row_start, bsums);
    scan2_kernel<<<1, 64, 0, stream>>>(bsums, SCAN_BLOCKS);
    scan3_kernel<<<SCAN_BLOCKS, 256, 0, stream>>>(row_start, bsums);
    scatter_kernel<<<(N_EDGES + 255) / 256, 256, 0, stream>>>(ei, et, row_start, epos, csr);
    attn_kernel<<<N_NODES / 4, 256, 0, stream>>>(
        (const unsigned int*)qb16, (const unsigned int*)kv16, rel,
        (const unsigned int*)relbf, row_start, csr, abuf);
    out_mfma_kernel<<<(N_NODES + 63) / 64, 256, 0, stream>>>(
        (const unsigned short*)abuf, Wt + (size_t)3 * HID * HID, bo, out);
}

// Round 7
// 247.355 us; speedup vs baseline: 2.0985x; 1.0594x over previous
//
#include <hip/hip_runtime.h>
#include <math.h>

#define N_NODES 50000
#define N_EDGES 800000
#define HID 128
#define HEADS 8
#define HDIM 16
#define CNT_BLOCKS 3125   // N_EDGES / 256
#define QKV_BLOCKS 782    // ceil(N_NODES / 64)

typedef __attribute__((ext_vector_type(8))) short short8;
typedef __attribute__((ext_vector_type(4))) float floatx4;

#if defined(__has_builtin)
#if __has_builtin(__builtin_amdgcn_fdot2_f32_bf16)
#define HAVE_DOT2 1
#endif
#endif
#ifndef HAVE_DOT2
#define HAVE_DOT2 0
#endif

#if HAVE_DOT2
typedef __attribute__((ext_vector_type(2))) __bf16 bf16x2;
__device__ __forceinline__ float dot2acc(unsigned int a, unsigned int b, float c) {
    return __builtin_amdgcn_fdot2_f32_bf16(__builtin_bit_cast(bf16x2, a),
                                           __builtin_bit_cast(bf16x2, b), c, false);
}
#endif

__device__ __forceinline__ float bf_lo(unsigned int d) { return __uint_as_float(d << 16); }
__device__ __forceinline__ float bf_hi(unsigned int d) { return __uint_as_float(d & 0xFFFF0000u); }
__device__ __forceinline__ unsigned short f2bf(float f) {
    unsigned int u = __float_as_uint(f);
    u = (u + 0x7FFFu + ((u >> 16) & 1u)) >> 16;  // RNE
    return (unsigned short)u;
}
__device__ __forceinline__ unsigned int pack_bf2(float a, float b) {
    return (unsigned int)f2bf(a) | ((unsigned int)f2bf(b) << 16);
}

// ---------------- fused: edge count (+slot record) | weight->bf16 transpose |
// rel->bf16 | query bias fold.  Blocks [0,CNT_BLOCKS) count; rest prep. ----------------
__global__ __launch_bounds__(256) void prep_count_kernel(
    const float* __restrict__ query, const float* __restrict__ rel,
    const float* __restrict__ Wq, const float* __restrict__ bq,
    const float* __restrict__ Wk, const float* __restrict__ bk,
    const float* __restrict__ Wv, const float* __restrict__ Wo,
    const int* __restrict__ ei,
    unsigned short* __restrict__ Wt, unsigned short* __restrict__ relbf,
    int* __restrict__ counts, int* __restrict__ epos,
    float* __restrict__ bqe, float* __restrict__ bke) {
    int b = blockIdx.x;
    if (b < CNT_BLOCKS) {
        int e = b * 256 + threadIdx.x;
        if (e < N_EDGES) epos[e] = atomicAdd(&counts[ei[N_EDGES + e]], 1);
        return;
    }
    b -= CNT_BLOCKS;
    if (b == 256) {
        int j = threadIdx.x;
        if (j < HID) {
            float aq = bq[j], ak = bk[j];
            for (int i = 0; i < HID; ++i) {
                float qv = query[i];
                aq += qv * Wq[(HID + i) * HID + j];
                ak += qv * Wk[(HID + i) * HID + j];
            }
            bqe[j] = aq;
            bke[j] = ak;
        }
        return;
    }
    int idx = b * 256 + threadIdx.x;  // < 65536
    if (idx < 64 * HID) relbf[idx] = f2bf(rel[idx]);
    int m = idx >> 14;
    int rem = idx & 16383;
    int n = rem >> 7, k = rem & 127;
    const float* W = (m == 0) ? Wq : (m == 1) ? Wk : (m == 2) ? Wv : Wo;
    Wt[idx] = f2bf(W[k * HID + n]);  // Wq/Wk: rows 0..127 only (query part folded into bias)
}

// ---------------- scan stage 1: per-1024-chunk exclusive scan + chunk sums ----------------
__global__ __launch_bounds__(256) void scan1_kernel(const int* __restrict__ counts,
                                                    int* __restrict__ row_start,
                                                    int* __restrict__ bsums) {
    __shared__ int wsum[4];
    int b = blockIdx.x, tid = threadIdx.x, lane = tid & 63, w = tid >> 6;
    int i0 = b * 1024 + tid * 4;
    int x0 = (i0 + 0 < N_NODES) ? counts[i0 + 0] : 0;
    int x1 = (i0 + 1 < N_NODES) ? counts[i0 + 1] : 0;
    int x2 = (i0 + 2 < N_NODES) ? counts[i0 + 2] : 0;
    int x3 = (i0 + 3 < N_NODES) ? counts[i0 + 3] : 0;
    int t = x0 + x1 + x2 + x3;
    int val = t;
    #pragma unroll
    for (int off = 1; off < 64; off <<= 1) {
        int y = __shfl_up(val, off);
        if (lane >= off) val += y;
    }
    if (lane == 63) wsum[w] = val;
    __syncthreads();
    int wo = 0;
    if (w > 0) wo += wsum[0];
    if (w > 1) wo += wsum[1];
    if (w > 2) wo += wsum[2];
    int excl = wo + val - t;
    if (i0 + 0 < N_NODES) row_start[i0 + 0] = excl;
    if (i0 + 1 < N_NODES) row_start[i0 + 1] = excl + x0;
    if (i0 + 2 < N_NODES) row_start[i0 + 2] = excl + x0 + x1;
    if (i0 + 3 < N_NODES) row_start[i0 + 3] = excl + x0 + x1 + x2;
    if (tid == 255) bsums[b] = wo + val;
}

// ---------------- scan stage 2+3 merged: each block derives its own offset ----------------
__global__ __launch_bounds__(256) void scan23_kernel(int* __restrict__ row_start,
                                                     const int* __restrict__ bsums) {
    __shared__ int soff;
    int b = blockIdx.x, tid = threadIdx.x;
    if (tid < 64) {
        int x = (tid < b) ? bsums[tid] : 0;
        #pragma unroll
        for (int off = 32; off > 0; off >>= 1) x += __shfl_down(x, off);
        if (tid == 0) soff = x;
    }
    __syncthreads();
    int off = soff;
    int i0 = b * 1024 + tid * 4;
    if (i0 + 3 < N_NODES) {
        int4* p = (int4*)(row_start + i0);
        int4 v = *p;
        v.x += off; v.y += off; v.z += off; v.w += off;
        *p = v;
    } else {
        for (int j = 0; j < 4; ++j)
            if (i0 + j < N_NODES) row_start[i0 + j] += off;
    }
    if (b == 0 && tid == 0) row_start[N_NODES] = N_EDGES;
}

// ---------------- fused: QKV MFMA | CSR scatter.  Blocks [0,QKV_BLOCKS) qkv;
// rest scatter (independent work, hides scatter's random writes). ----------------
__global__ __launch_bounds__(256) void qkv_scatter_kernel(
    const float* __restrict__ nf, const unsigned short* __restrict__ Wt,
    const float* __restrict__ bqe, const float* __restrict__ bke, const float* __restrict__ bv,
    const int* __restrict__ ei, const int* __restrict__ et,
    const int* __restrict__ row_start, const int* __restrict__ epos,
    unsigned short* __restrict__ qb16, unsigned short* __restrict__ kv16,
    unsigned int* __restrict__ csr) {
    if (blockIdx.x >= QKV_BLOCKS) {
        int e = (blockIdx.x - QKV_BLOCKS) * 256 + threadIdx.x;
        if (e < N_EDGES) {
            int dst = ei[N_EDGES + e];
            csr[row_start[dst] + epos[e]] = ((unsigned int)et[e] << 18) | (unsigned int)ei[e];
        }
        return;
    }
    int row0 = blockIdx.x * 64;
    int wave = threadIdx.x >> 6;   // n-range selector
    int lane = threadIdx.x & 63;
    int col  = lane & 15;
    int quad = lane >> 4;

    // A fragments for all 4 row-tiles, reused across 3 matrices x 2 n-tiles.
    short8 afr[4][4];
    #pragma unroll
    for (int t = 0; t < 4; ++t) {
        int arow = row0 + t * 16 + col;
        int asafe = (arow < N_NODES) ? arow : (N_NODES - 1);
        #pragma unroll
        for (int kk = 0; kk < 4; ++kk) {
            const float4* ap = (const float4*)(nf + (size_t)asafe * HID + kk * 32 + quad * 8);
            float4 a0 = ap[0], a1 = ap[1];
            short8 f;
            f[0] = (short)f2bf(a0.x); f[1] = (short)f2bf(a0.y);
            f[2] = (short)f2bf(a0.z); f[3] = (short)f2bf(a0.w);
            f[4] = (short)f2bf(a1.x); f[5] = (short)f2bf(a1.y);
            f[6] = (short)f2bf(a1.z); f[7] = (short)f2bf(a1.w);
            afr[t][kk] = f;
        }
    }

    const float* biases[3] = {bqe, bke, bv};
    #pragma unroll
    for (int m = 0; m < 3; ++m) {
        const unsigned short* W = Wt + (size_t)m * HID * HID;
        #pragma unroll
        for (int nn = 0; nn < 2; ++nn) {
            int n = wave * 2 + nn;
            float b = biases[m][n * 16 + col];
            floatx4 acc[4];
            #pragma unroll
            for (int t = 0; t < 4; ++t) acc[t] = (floatx4){b, b, b, b};
            short8 bfr[4];
            #pragma unroll
            for (int kk = 0; kk < 4; ++kk)
                bfr[kk] = *(const short8*)(W + (size_t)(n * 16 + col) * HID + kk * 32 + quad * 8);
            #pragma unroll
            for (int kk = 0; kk < 4; ++kk)
                #pragma unroll
                for (int t = 0; t < 4; ++t)
                    acc[t] = __builtin_amdgcn_mfma_f32_16x16x32_bf16(afr[t][kk], bfr[kk], acc[t], 0, 0, 0);
            #pragma unroll
            for (int t = 0; t < 4; ++t) {
                #pragma unroll
                for (int i = 0; i < 4; ++i) {
                    int r = row0 + t * 16 + quad * 4 + i;
                    if (r < N_NODES) {
                        int c = n * 16 + col;
                        if (m == 0)      qb16[(size_t)r * HID + c] = f2bf(acc[t][i]);
                        else if (m == 1) kv16[(size_t)r * 256 + c] = f2bf(acc[t][i]);
                        else             kv16[(size_t)r * 256 + 128 + c] = f2bf(acc[t][i]);
                    }
                }
            }
        }
    }
}

// ---------------- out = Abf16 @ Wo + bo via MFMA (N-split waves), fp32 out ----------------
__global__ __launch_bounds__(256) void out_mfma_kernel(
    const unsigned short* __restrict__ abuf, const unsigned short* __restrict__ Wot,
    const float* __restrict__ bo, float* __restrict__ out) {
    int row0 = blockIdx.x * 64;
    int wave = threadIdx.x >> 6;
    int lane = threadIdx.x & 63;
    int col  = lane & 15;
    int quad = lane >> 4;

    short8 afr[4][4];
    #pragma unroll
    for (int t = 0; t < 4; ++t) {
        int arow = row0 + t * 16 + col;
        int asafe = (arow < N_NODES) ? arow : (N_NODES - 1);
        #pragma unroll
        for (int kk = 0; kk < 4; ++kk)
            afr[t][kk] = *(const short8*)(abuf + (size_t)asafe * HID + kk * 32 + quad * 8);
    }

    #pragma unroll
    for (int nn = 0; nn < 2; ++nn) {
        int n = wave * 2 + nn;
        float b = bo[n * 16 + col];
        floatx4 acc[4];
        #pragma unroll
        for (int t = 0; t < 4; ++t) acc[t] = (floatx4){b, b, b, b};
        short8 bfr[4];
        #pragma unroll
        for (int kk = 0; kk < 4; ++kk)
            bfr[kk] = *(const short8*)(Wot + (size_t)(n * 16 + col) * HID + kk * 32 + quad * 8);
        #pragma unroll
        for (int kk = 0; kk < 4; ++kk)
            #pragma unroll
            for (int t = 0; t < 4; ++t)
                acc[t] = __builtin_amdgcn_mfma_f32_16x16x32_bf16(afr[t][kk], bfr[kk], acc[t], 0, 0, 0);
        #pragma unroll
        for (int t = 0; t < 4; ++t) {
            #pragma unroll
            for (int i = 0; i < 4; ++i) {
                int r = row0 + t * 16 + quad * 4 + i;
                if (r < N_NODES) out[(size_t)r * HID + n * 16 + col] = acc[t][i];
            }
        }
    }
}

// ---------------- single-pass wave-per-node attention ----------------
// csr load software-pipelined one iteration ahead; score dot product split
// into 4 parallel accumulator chains (dep chain ~24 cyc vs 64).
__global__ __launch_bounds__(256) void attn_kernel(
    const unsigned int* __restrict__ qb, const unsigned int* __restrict__ kvu,
    const float* __restrict__ rel, const unsigned int* __restrict__ relu,
    const int* __restrict__ row_start, const unsigned int* __restrict__ csr,
    unsigned int* __restrict__ abuf) {
    int node = blockIdx.x * 4 + (threadIdx.x >> 6);
    int lane = threadIdx.x & 63;
    int h = lane & 7;
    int hd = lane >> 3;
    int rs = row_start[node];
    int deg = row_start[node + 1] - rs;

    const uint4* qp = (const uint4*)(qb + (size_t)node * 64 + h * 8);
    uint4 qa = qp[0], qc = qp[1];
#if !HAVE_DOT2
    float qf0 = bf_lo(qa.x), qf1 = bf_hi(qa.x), qf2 = bf_lo(qa.y), qf3 = bf_hi(qa.y);
    float qf4 = bf_lo(qa.z), qf5 = bf_hi(qa.z), qf6 = bf_lo(qa.w), qf7 = bf_hi(qa.w);
    float qf8 = bf_lo(qc.x), qf9 = bf_hi(qc.x), qf10 = bf_lo(qc.y), qf11 = bf_hi(qc.y);
    float qf12 = bf_lo(qc.z), qf13 = bf_hi(qc.z), qf14 = bf_lo(qc.w), qf15 = bf_hi(qc.w);
#endif

    int myel = lane >> 3;
    unsigned int pk = (myel < deg) ? csr[rs + myel] : 0u;
    float ssum = 0.0f, accx = 0.0f, accy = 0.0f;
    for (int base = 0; base < deg; base += 8) {
        int el = base + myel;
        int eln = el + 8;
        unsigned int pk_next = (eln < deg) ? csr[rs + eln] : 0u;  // prefetch
        float w = 0.0f;
        int src = 0;
        if (el < deg) {
            src = pk & 0x3FFFF;
            int etv = (int)(pk >> 18);
            const uint4* kp = (const uint4*)(kvu + (size_t)src * 128 + h * 8);
            uint4 ka = kp[0], kb = kp[1];
            float s;
#if HAVE_DOT2
            const uint4* rp = (const uint4*)(relu + (size_t)etv * 64 + h * 8);
            uint4 ra = rp[0], rb = rp[1];
            float s0 = dot2acc(qa.x, ka.x, 0.0f);
            float s1 = dot2acc(qa.y, ka.y, 0.0f);
            float s2 = dot2acc(qa.z, ka.z, 0.0f);
            float s3 = dot2acc(qa.w, ka.w, 0.0f);
            s0 = dot2acc(qc.x, kb.x, s0);
            s1 = dot2acc(qc.y, kb.y, s1);
            s2 = dot2acc(qc.z, kb.z, s2);
            s3 = dot2acc(qc.w, kb.w, s3);
            s0 = dot2acc(qa.x, ra.x, s0);
            s1 = dot2acc(qa.y, ra.y, s1);
            s2 = dot2acc(qa.z, ra.z, s2);
            s3 = dot2acc(qa.w, ra.w, s3);
            s0 = dot2acc(qc.x, rb.x, s0);
            s1 = dot2acc(qc.y, rb.y, s1);
            s2 = dot2acc(qc.z, rb.z, s2);
            s3 = dot2acc(qc.w, rb.w, s3);
            s = (s0 + s1) + (s2 + s3);
#else
            const float4* rp = (const float4*)(rel + (size_t)etv * HID + h * HDIM);
            float4 r0 = rp[0], r1 = rp[1], r2 = rp[2], r3 = rp[3];
            float s0 = qf0 * (bf_lo(ka.x) + r0.x) + qf4 * (bf_lo(ka.z) + r1.x)
                     + qf8 * (bf_lo(kb.x) + r2.x) + qf12 * (bf_lo(kb.z) + r3.x);
            float s1 = qf1 * (bf_hi(ka.x) + r0.y) + qf5 * (bf_hi(ka.z) + r1.y)
                     + qf9 * (bf_hi(kb.x) + r2.y) + qf13 * (bf_hi(kb.z) + r3.y);
            float s2 = qf2 * (bf_lo(ka.y) + r0.z) + qf6 * (bf_lo(ka.w) + r1.z)
                     + qf10 * (bf_lo(kb.y) + r2.z) + qf14 * (bf_lo(kb.w) + r3.z);
            float s3 = qf3 * (bf_hi(ka.y) + r0.w) + qf7 * (bf_hi(ka.w) + r1.w)
                     + qf11 * (bf_hi(kb.y) + r2.w) + qf15 * (bf_hi(kb.w) + r3.w);
            s = (s0 + s1) + (s2 + s3);
#endif
            w = __expf(s * 0.25f);  // / sqrt(16)
            ssum += w;
        }
        #pragma unroll
        for (int j = 0; j < 8; ++j) {
            int   sj = __shfl(src, j * 8);
            float wj = __shfl(w, j * 8 + hd);
            unsigned int vp = kvu[(size_t)sj * 128 + 64 + lane];
            accx += wj * bf_lo(vp);
            accy += wj * bf_hi(vp);
        }
        pk = pk_next;
    }
    #pragma unroll
    for (int off = 8; off < 64; off <<= 1) ssum += __shfl_xor(ssum, off);
    float inv = 1.0f / (__shfl(ssum, hd) + 1e-8f);
    abuf[(size_t)node * 64 + lane] = pack_bf2(accx * inv, accy * inv);
}

extern "C" void kernel_launch(void* const* d_in, const int* in_sizes, int n_in,
                              void* d_out, int out_size, void* d_ws, size_t ws_size,
                              hipStream_t stream) {
    const float* nf    = (const float*)d_in[0];
    const float* query = (const float*)d_in[1];
    const float* rel   = (const float*)d_in[2];
    const float* Wq    = (const float*)d_in[3];
    const float* bq    = (const float*)d_in[4];
    const float* Wk    = (const float*)d_in[5];
    const float* bk    = (const float*)d_in[6];
    const float* Wv    = (const float*)d_in[7];
    const float* bv    = (const float*)d_in[8];
    const float* Wo    = (const float*)d_in[9];
    const float* bo    = (const float*)d_in[10];
    const int*   ei    = (const int*)d_in[11];
    const int*   et    = (const int*)d_in[12];
    float* out = (float*)d_out;

    char* ws = (char*)d_ws;
    unsigned short* qb16 = (unsigned short*)ws; ws += (size_t)N_NODES * HID * 2;
    unsigned short* kv16 = (unsigned short*)ws; ws += (size_t)N_NODES * 256 * 2;
    unsigned int* abuf   = (unsigned int*)ws;   ws += (size_t)N_NODES * 64 * 4;
    float* bqe           = (float*)ws;          ws += 128 * 4;
    float* bke           = (float*)ws;          ws += 128 * 4;
    int* row_start       = (int*)ws;            ws += (size_t)(N_NODES + 4) * 4;
    int* counts          = (int*)ws;            ws += (size_t)N_NODES * 4;
    int* epos            = (int*)ws;            ws += (size_t)N_EDGES * 4;
    int* bsums           = (int*)ws;            ws += 64 * 4;
    unsigned int* csr    = (unsigned int*)ws;   ws += (size_t)N_EDGES * 4;
    unsigned short* Wt   = (unsigned short*)ws; ws += (size_t)4 * HID * HID * 2;
    unsigned short* relbf = (unsigned short*)ws; ws += (size_t)64 * HID * 2;

    const int SCAN_BLOCKS = (N_NODES + 1023) / 1024;  // 49

    hipMemsetAsync(counts, 0, (size_t)N_NODES * 4, stream);
    prep_count_kernel<<<CNT_BLOCKS + 257, 256, 0, stream>>>(
        query, rel, Wq, bq, Wk, bk, Wv, Wo, ei, Wt, relbf, counts, epos, bqe, bke);
    scan1_kernel<<<SCAN_BLOCKS, 256, 0, stream>>>(counts, row_start, bsums);
    scan23_kernel<<<SCAN_BLOCKS, 256, 0, stream>>>(row_start, bsums);
    qkv_scatter_kernel<<<QKV_BLOCKS + CNT_BLOCKS, 256, 0, stream>>>(
        nf, Wt, bqe, bke, bv, ei, et, row_start, epos, qb16, kv16, csr);
    attn_kernel<<<N_NODES / 4, 256, 0, stream>>>(
        (const unsigned int*)qb16, (const unsigned int*)kv16, rel,
        (const unsigned int*)relbf, row_start, csr, abuf);
    out_mfma_kernel<<<QKV_BLOCKS, 256, 0, stream>>>(
        (const unsigned short*)abuf, Wt + (size_t)3 * HID * HID, bo, out);
}

// Round 8
// 246.048 us; speedup vs baseline: 2.1096x; 1.0053x over previous
//
#include <hip/hip_runtime.h>
#include <math.h>

#define N_NODES 50000
#define N_EDGES 800000
#define HID 128
#define HEADS 8
#define HDIM 16
#define CNT_BLOCKS 3125   // N_EDGES / 256
#define QKV_BLOCKS 782    // ceil(N_NODES / 64)

typedef __attribute__((ext_vector_type(8))) short short8;
typedef __attribute__((ext_vector_type(4))) float floatx4;

#if defined(__has_builtin)
#if __has_builtin(__builtin_amdgcn_fdot2_f32_bf16)
#define HAVE_DOT2 1
#endif
#endif
#ifndef HAVE_DOT2
#define HAVE_DOT2 0
#endif

#if HAVE_DOT2
typedef __attribute__((ext_vector_type(2))) __bf16 bf16x2;
__device__ __forceinline__ float dot2acc(unsigned int a, unsigned int b, float c) {
    return __builtin_amdgcn_fdot2_f32_bf16(__builtin_bit_cast(bf16x2, a),
                                           __builtin_bit_cast(bf16x2, b), c, false);
}
#endif

__device__ __forceinline__ float bf_lo(unsigned int d) { return __uint_as_float(d << 16); }
__device__ __forceinline__ float bf_hi(unsigned int d) { return __uint_as_float(d & 0xFFFF0000u); }
__device__ __forceinline__ unsigned short f2bf(float f) {
    unsigned int u = __float_as_uint(f);
    u = (u + 0x7FFFu + ((u >> 16) & 1u)) >> 16;  // RNE
    return (unsigned short)u;
}
__device__ __forceinline__ unsigned int pack_bf2(float a, float b) {
    return (unsigned int)f2bf(a) | ((unsigned int)f2bf(b) << 16);
}

// ---------------- fused: edge count (+slot record) | weight->bf16 transpose |
// rel->bf16 | query bias fold.  Blocks [0,CNT_BLOCKS) count; rest prep. ----------------
__global__ __launch_bounds__(256) void prep_count_kernel(
    const float* __restrict__ query, const float* __restrict__ rel,
    const float* __restrict__ Wq, const float* __restrict__ bq,
    const float* __restrict__ Wk, const float* __restrict__ bk,
    const float* __restrict__ Wv, const float* __restrict__ Wo,
    const int* __restrict__ ei,
    unsigned short* __restrict__ Wt, unsigned short* __restrict__ relbf,
    int* __restrict__ counts, int* __restrict__ epos,
    float* __restrict__ bqe, float* __restrict__ bke) {
    int b = blockIdx.x;
    if (b < CNT_BLOCKS) {
        int e = b * 256 + threadIdx.x;
        if (e < N_EDGES) epos[e] = atomicAdd(&counts[ei[N_EDGES + e]], 1);
        return;
    }
    b -= CNT_BLOCKS;
    if (b == 256) {
        int j = threadIdx.x;
        if (j < HID) {
            float aq = bq[j], ak = bk[j];
            for (int i = 0; i < HID; ++i) {
                float qv = query[i];
                aq += qv * Wq[(HID + i) * HID + j];
                ak += qv * Wk[(HID + i) * HID + j];
            }
            bqe[j] = aq;
            bke[j] = ak;
        }
        return;
    }
    int idx = b * 256 + threadIdx.x;  // < 65536
    if (idx < 64 * HID) relbf[idx] = f2bf(rel[idx]);
    int m = idx >> 14;
    int rem = idx & 16383;
    int n = rem >> 7, k = rem & 127;
    const float* W = (m == 0) ? Wq : (m == 1) ? Wk : (m == 2) ? Wv : Wo;
    Wt[idx] = f2bf(W[k * HID + n]);  // Wq/Wk: rows 0..127 only (query part folded into bias)
}

// ---------------- scan stage 1: per-1024-chunk exclusive scan + chunk sums ----------------
__global__ __launch_bounds__(256) void scan1_kernel(const int* __restrict__ counts,
                                                    int* __restrict__ row_start,
                                                    int* __restrict__ bsums) {
    __shared__ int wsum[4];
    int b = blockIdx.x, tid = threadIdx.x, lane = tid & 63, w = tid >> 6;
    int i0 = b * 1024 + tid * 4;
    int x0 = (i0 + 0 < N_NODES) ? counts[i0 + 0] : 0;
    int x1 = (i0 + 1 < N_NODES) ? counts[i0 + 1] : 0;
    int x2 = (i0 + 2 < N_NODES) ? counts[i0 + 2] : 0;
    int x3 = (i0 + 3 < N_NODES) ? counts[i0 + 3] : 0;
    int t = x0 + x1 + x2 + x3;
    int val = t;
    #pragma unroll
    for (int off = 1; off < 64; off <<= 1) {
        int y = __shfl_up(val, off);
        if (lane >= off) val += y;
    }
    if (lane == 63) wsum[w] = val;
    __syncthreads();
    int wo = 0;
    if (w > 0) wo += wsum[0];
    if (w > 1) wo += wsum[1];
    if (w > 2) wo += wsum[2];
    int excl = wo + val - t;
    if (i0 + 0 < N_NODES) row_start[i0 + 0] = excl;
    if (i0 + 1 < N_NODES) row_start[i0 + 1] = excl + x0;
    if (i0 + 2 < N_NODES) row_start[i0 + 2] = excl + x0 + x1;
    if (i0 + 3 < N_NODES) row_start[i0 + 3] = excl + x0 + x1 + x2;
    if (tid == 255) bsums[b] = wo + val;
}

// ---------------- scan stage 2+3 merged: each block derives its own offset ----------------
__global__ __launch_bounds__(256) void scan23_kernel(int* __restrict__ row_start,
                                                     const int* __restrict__ bsums) {
    __shared__ int soff;
    int b = blockIdx.x, tid = threadIdx.x;
    if (tid < 64) {
        int x = (tid < b) ? bsums[tid] : 0;
        #pragma unroll
        for (int off = 32; off > 0; off >>= 1) x += __shfl_down(x, off);
        if (tid == 0) soff = x;
    }
    __syncthreads();
    int off = soff;
    int i0 = b * 1024 + tid * 4;
    if (i0 + 3 < N_NODES) {
        int4* p = (int4*)(row_start + i0);
        int4 v = *p;
        v.x += off; v.y += off; v.z += off; v.w += off;
        *p = v;
    } else {
        for (int j = 0; j < 4; ++j)
            if (i0 + j < N_NODES) row_start[i0 + j] += off;
    }
    if (b == 0 && tid == 0) row_start[N_NODES] = N_EDGES;
}

// ---------------- fused: QKV MFMA | CSR scatter ----------------
__global__ __launch_bounds__(256) void qkv_scatter_kernel(
    const float* __restrict__ nf, const unsigned short* __restrict__ Wt,
    const float* __restrict__ bqe, const float* __restrict__ bke, const float* __restrict__ bv,
    const int* __restrict__ ei, const int* __restrict__ et,
    const int* __restrict__ row_start, const int* __restrict__ epos,
    unsigned short* __restrict__ qb16, unsigned short* __restrict__ kv16,
    unsigned int* __restrict__ csr) {
    if (blockIdx.x >= QKV_BLOCKS) {
        int e = (blockIdx.x - QKV_BLOCKS) * 256 + threadIdx.x;
        if (e < N_EDGES) {
            int dst = ei[N_EDGES + e];
            csr[row_start[dst] + epos[e]] = ((unsigned int)et[e] << 18) | (unsigned int)ei[e];
        }
        return;
    }
    int row0 = blockIdx.x * 64;
    int wave = threadIdx.x >> 6;   // n-range selector
    int lane = threadIdx.x & 63;
    int col  = lane & 15;
    int quad = lane >> 4;

    short8 afr[4][4];
    #pragma unroll
    for (int t = 0; t < 4; ++t) {
        int arow = row0 + t * 16 + col;
        int asafe = (arow < N_NODES) ? arow : (N_NODES - 1);
        #pragma unroll
        for (int kk = 0; kk < 4; ++kk) {
            const float4* ap = (const float4*)(nf + (size_t)asafe * HID + kk * 32 + quad * 8);
            float4 a0 = ap[0], a1 = ap[1];
            short8 f;
            f[0] = (short)f2bf(a0.x); f[1] = (short)f2bf(a0.y);
            f[2] = (short)f2bf(a0.z); f[3] = (short)f2bf(a0.w);
            f[4] = (short)f2bf(a1.x); f[5] = (short)f2bf(a1.y);
            f[6] = (short)f2bf(a1.z); f[7] = (short)f2bf(a1.w);
            afr[t][kk] = f;
        }
    }

    const float* biases[3] = {bqe, bke, bv};
    #pragma unroll
    for (int m = 0; m < 3; ++m) {
        const unsigned short* W = Wt + (size_t)m * HID * HID;
        #pragma unroll
        for (int nn = 0; nn < 2; ++nn) {
            int n = wave * 2 + nn;
            float b = biases[m][n * 16 + col];
            floatx4 acc[4];
            #pragma unroll
            for (int t = 0; t < 4; ++t) acc[t] = (floatx4){b, b, b, b};
            short8 bfr[4];
            #pragma unroll
            for (int kk = 0; kk < 4; ++kk)
                bfr[kk] = *(const short8*)(W + (size_t)(n * 16 + col) * HID + kk * 32 + quad * 8);
            #pragma unroll
            for (int kk = 0; kk < 4; ++kk)
                #pragma unroll
                for (int t = 0; t < 4; ++t)
                    acc[t] = __builtin_amdgcn_mfma_f32_16x16x32_bf16(afr[t][kk], bfr[kk], acc[t], 0, 0, 0);
            #pragma unroll
            for (int t = 0; t < 4; ++t) {
                #pragma unroll
                for (int i = 0; i < 4; ++i) {
                    int r = row0 + t * 16 + quad * 4 + i;
                    if (r < N_NODES) {
                        int c = n * 16 + col;
                        if (m == 0)      qb16[(size_t)r * HID + c] = f2bf(acc[t][i]);
                        else if (m == 1) kv16[(size_t)r * 256 + c] = f2bf(acc[t][i]);
                        else             kv16[(size_t)r * 256 + 128 + c] = f2bf(acc[t][i]);
                    }
                }
            }
        }
    }
}

// ---------------- out = Abf16 @ Wo + bo via MFMA (N-split waves), fp32 out ----------------
__global__ __launch_bounds__(256) void out_mfma_kernel(
    const unsigned short* __restrict__ abuf, const unsigned short* __restrict__ Wot,
    const float* __restrict__ bo, float* __restrict__ out) {
    int row0 = blockIdx.x * 64;
    int wave = threadIdx.x >> 6;
    int lane = threadIdx.x & 63;
    int col  = lane & 15;
    int quad = lane >> 4;

    short8 afr[4][4];
    #pragma unroll
    for (int t = 0; t < 4; ++t) {
        int arow = row0 + t * 16 + col;
        int asafe = (arow < N_NODES) ? arow : (N_NODES - 1);
        #pragma unroll
        for (int kk = 0; kk < 4; ++kk)
            afr[t][kk] = *(const short8*)(abuf + (size_t)asafe * HID + kk * 32 + quad * 8);
    }

    #pragma unroll
    for (int nn = 0; nn < 2; ++nn) {
        int n = wave * 2 + nn;
        float b = bo[n * 16 + col];
        floatx4 acc[4];
        #pragma unroll
        for (int t = 0; t < 4; ++t) acc[t] = (floatx4){b, b, b, b};
        short8 bfr[4];
        #pragma unroll
        for (int kk = 0; kk < 4; ++kk)
            bfr[kk] = *(const short8*)(Wot + (size_t)(n * 16 + col) * HID + kk * 32 + quad * 8);
        #pragma unroll
        for (int kk = 0; kk < 4; ++kk)
            #pragma unroll
            for (int t = 0; t < 4; ++t)
                acc[t] = __builtin_amdgcn_mfma_f32_16x16x32_bf16(afr[t][kk], bfr[kk], acc[t], 0, 0, 0);
        #pragma unroll
        for (int t = 0; t < 4; ++t) {
            #pragma unroll
            for (int i = 0; i < 4; ++i) {
                int r = row0 + t * 16 + quad * 4 + i;
                if (r < N_NODES) out[(size_t)r * HID + n * 16 + col] = acc[t][i];
            }
        }
    }
}

// ---------------- attention: 2 waves per node, single packed shuffle per edge ----------------
// Lane = (edge-slot<<3) | head. w rounded to bf16 and packed with src (16 bits)
// -> one ds_bpermute per edge in the PV loop. Waves split edges; LDS combine.
__global__ __launch_bounds__(256) void attn_kernel(
    const unsigned int* __restrict__ qb, const unsigned int* __restrict__ kvu,
    const unsigned int* __restrict__ relu,
    const int* __restrict__ row_start, const unsigned int* __restrict__ csr,
    unsigned int* __restrict__ abuf) {
    __shared__ float lds_acc[2][64][2];
    __shared__ float lds_ssum[2][2][8];
    int slot = threadIdx.x >> 7;        // node within block
    int wv   = (threadIdx.x >> 6) & 1;  // wave within node
    int node = blockIdx.x * 2 + slot;
    int lane = threadIdx.x & 63;
    int h = lane & 7;
    int hd = lane >> 3;
    int rs = row_start[node];
    int deg = row_start[node + 1] - rs;

    const uint4* qp = (const uint4*)(qb + (unsigned)node * 64 + h * 8);
    uint4 qa = qp[0], qc = qp[1];
#if !HAVE_DOT2
    float qf0 = bf_lo(qa.x), qf1 = bf_hi(qa.x), qf2 = bf_lo(qa.y), qf3 = bf_hi(qa.y);
    float qf4 = bf_lo(qa.z), qf5 = bf_hi(qa.z), qf6 = bf_lo(qa.w), qf7 = bf_hi(qa.w);
    float qf8 = bf_lo(qc.x), qf9 = bf_hi(qc.x), qf10 = bf_lo(qc.y), qf11 = bf_hi(qc.y);
    float qf12 = bf_lo(qc.z), qf13 = bf_hi(qc.z), qf14 = bf_lo(qc.w), qf15 = bf_hi(qc.w);
#endif

    int myel0 = wv * 8 + (lane >> 3);
    float ssum = 0.0f, accx = 0.0f, accy = 0.0f;
    for (int base = 0; base < deg; base += 16) {
        int el = base + myel0;
        unsigned int pw = 0u;
        if (el < deg) {
            unsigned int pk = csr[rs + el];
            unsigned int src = pk & 0x3FFFF;
            unsigned int etv = pk >> 18;
            const uint4* kp = (const uint4*)(kvu + (src << 7) + h * 8);
            uint4 ka = kp[0], kb = kp[1];
            const uint4* rp = (const uint4*)(relu + (etv << 6) + h * 8);
            uint4 ra = rp[0], rb = rp[1];
            float s;
#if HAVE_DOT2
            float s0 = dot2acc(qa.x, ka.x, 0.0f);
            float s1 = dot2acc(qa.y, ka.y, 0.0f);
            float s2 = dot2acc(qa.z, ka.z, 0.0f);
            float s3 = dot2acc(qa.w, ka.w, 0.0f);
            s0 = dot2acc(qc.x, kb.x, s0);
            s1 = dot2acc(qc.y, kb.y, s1);
            s2 = dot2acc(qc.z, kb.z, s2);
            s3 = dot2acc(qc.w, kb.w, s3);
            s0 = dot2acc(qa.x, ra.x, s0);
            s1 = dot2acc(qa.y, ra.y, s1);
            s2 = dot2acc(qa.z, ra.z, s2);
            s3 = dot2acc(qa.w, ra.w, s3);
            s0 = dot2acc(qc.x, rb.x, s0);
            s1 = dot2acc(qc.y, rb.y, s1);
            s2 = dot2acc(qc.z, rb.z, s2);
            s3 = dot2acc(qc.w, rb.w, s3);
            s = (s0 + s1) + (s2 + s3);
#else
            float s0 = qf0 * (bf_lo(ka.x) + bf_lo(ra.x)) + qf4 * (bf_lo(ka.z) + bf_lo(ra.z))
                     + qf8 * (bf_lo(kb.x) + bf_lo(rb.x)) + qf12 * (bf_lo(kb.z) + bf_lo(rb.z));
            float s1 = qf1 * (bf_hi(ka.x) + bf_hi(ra.x)) + qf5 * (bf_hi(ka.z) + bf_hi(ra.z))
                     + qf9 * (bf_hi(kb.x) + bf_hi(rb.x)) + qf13 * (bf_hi(kb.z) + bf_hi(rb.z));
            float s2 = qf2 * (bf_lo(ka.y) + bf_lo(ra.y)) + qf6 * (bf_lo(ka.w) + bf_lo(ra.w))
                     + qf10 * (bf_lo(kb.y) + bf_lo(rb.y)) + qf14 * (bf_lo(kb.w) + bf_lo(rb.w));
            float s3 = qf3 * (bf_hi(ka.y) + bf_hi(ra.y)) + qf7 * (bf_hi(ka.w) + bf_hi(ra.w))
                     + qf11 * (bf_hi(kb.y) + bf_hi(rb.y)) + qf15 * (bf_hi(kb.w) + bf_hi(rb.w));
            s = (s0 + s1) + (s2 + s3);
#endif
            float w = __expf(s * 0.25f);  // / sqrt(16)
            unsigned int wb = (unsigned int)f2bf(w);
            w = __uint_as_float(wb << 16);  // bf16-consistent weight
            ssum += w;
            pw = (wb << 16) | src;  // src < 65536
        }
        #pragma unroll
        for (int j = 0; j < 8; ++j) {
            unsigned int pj = __shfl(pw, j * 8 + hd);
            float wj = bf_hi(pj);
            unsigned int sj = pj & 0xFFFFu;
            unsigned int vp = kvu[(sj << 7) + 64 + lane];
            accx += wj * bf_lo(vp);
            accy += wj * bf_hi(vp);
        }
    }
    #pragma unroll
    for (int off = 8; off < 64; off <<= 1) ssum += __shfl_xor(ssum, off);

    if (lane < 8) lds_ssum[slot][wv][lane] = ssum;
    if (wv == 1) { lds_acc[slot][lane][0] = accx; lds_acc[slot][lane][1] = accy; }
    __syncthreads();
    if (wv == 0) {
        accx += lds_acc[slot][lane][0];
        accy += lds_acc[slot][lane][1];
        float stot = lds_ssum[slot][0][hd] + lds_ssum[slot][1][hd];
        float inv = 1.0f / (stot + 1e-8f);
        abuf[(unsigned)node * 64 + lane] = pack_bf2(accx * inv, accy * inv);
    }
}

extern "C" void kernel_launch(void* const* d_in, const int* in_sizes, int n_in,
                              void* d_out, int out_size, void* d_ws, size_t ws_size,
                              hipStream_t stream) {
    const float* nf    = (const float*)d_in[0];
    const float* query = (const float*)d_in[1];
    const float* rel   = (const float*)d_in[2];
    const float* Wq    = (const float*)d_in[3];
    const float* bq    = (const float*)d_in[4];
    const float* Wk    = (const float*)d_in[5];
    const float* bk    = (const float*)d_in[6];
    const float* Wv    = (const float*)d_in[7];
    const float* bv    = (const float*)d_in[8];
    const float* Wo    = (const float*)d_in[9];
    const float* bo    = (const float*)d_in[10];
    const int*   ei    = (const int*)d_in[11];
    const int*   et    = (const int*)d_in[12];
    float* out = (float*)d_out;

    char* ws = (char*)d_ws;
    unsigned short* qb16 = (unsigned short*)ws; ws += (size_t)N_NODES * HID * 2;
    unsigned short* kv16 = (unsigned short*)ws; ws += (size_t)N_NODES * 256 * 2;
    unsigned int* abuf   = (unsigned int*)ws;   ws += (size_t)N_NODES * 64 * 4;
    float* bqe           = (float*)ws;          ws += 128 * 4;
    float* bke           = (float*)ws;          ws += 128 * 4;
    int* row_start       = (int*)ws;            ws += (size_t)(N_NODES + 4) * 4;
    int* counts          = (int*)ws;            ws += (size_t)N_NODES * 4;
    int* epos            = (int*)ws;            ws += (size_t)N_EDGES * 4;
    int* bsums           = (int*)ws;            ws += 64 * 4;
    unsigned int* csr    = (unsigned int*)ws;   ws += (size_t)N_EDGES * 4;
    unsigned short* Wt   = (unsigned short*)ws; ws += (size_t)4 * HID * HID * 2;
    unsigned short* relbf = (unsigned short*)ws; ws += (size_t)64 * HID * 2;

    const int SCAN_BLOCKS = (N_NODES + 1023) / 1024;  // 49

    hipMemsetAsync(counts, 0, (size_t)N_NODES * 4, stream);
    prep_count_kernel<<<CNT_BLOCKS + 257, 256, 0, stream>>>(
        query, rel, Wq, bq, Wk, bk, Wv, Wo, ei, Wt, relbf, counts, epos, bqe, bke);
    scan1_kernel<<<SCAN_BLOCKS, 256, 0, stream>>>(counts, row_start, bsums);
    scan23_kernel<<<SCAN_BLOCKS, 256, 0, stream>>>(row_start, bsums);
    qkv_scatter_kernel<<<QKV_BLOCKS + CNT_BLOCKS, 256, 0, stream>>>(
        nf, Wt, bqe, bke, bv, ei, et, row_start, epos, qb16, kv16, csr);
    attn_kernel<<<N_NODES / 2, 256, 0, stream>>>(
        (const unsigned int*)qb16, (const unsigned int*)kv16,
        (const unsigned int*)relbf, row_start, csr, abuf);
    out_mfma_kernel<<<QKV_BLOCKS, 256, 0, stream>>>(
        (const unsigned short*)abuf, Wt + (size_t)3 * HID * HID, bo, out);
}